// Round 11
// baseline (11118.348 us; speedup 1.0000x reference)
//
#include <hip/hip_runtime.h>
#include <hip/hip_bf16.h>
#include <cstdint>
#include <cmath>

#define EPSLN 1e-5f

typedef __attribute__((ext_vector_type(8))) short bf16x8;
typedef __attribute__((ext_vector_type(4))) float f32x4;
typedef __attribute__((ext_vector_type(4))) unsigned short u16x4;

constexpr int Bc = 16;
constexpr int Sc = 129;          // T+1
constexpr int Mc = Bc * Sc;      // 2064 rows (real)
constexpr int MP = 2112;         // padded rows = 33*64 = 66*32
constexpr int ITERS = 127;       // T-1

__device__ __forceinline__ void gl2lds16(const void* g, void* l) {
    __builtin_amdgcn_global_load_lds(
        (const __attribute__((address_space(1))) unsigned int*)g,
        (__attribute__((address_space(3))) unsigned int*)l, 16, 0, 0);
}

template<int N> __device__ __forceinline__ void vmw() {
    if constexpr (N == 0) asm volatile("s_waitcnt vmcnt(0)" ::: "memory");
    else if constexpr (N == 3) asm volatile("s_waitcnt vmcnt(3)" ::: "memory");
    else if constexpr (N == 4) asm volatile("s_waitcnt vmcnt(4)" ::: "memory");
    else if constexpr (N == 6) asm volatile("s_waitcnt vmcnt(6)" ::: "memory");
}

__device__ __forceinline__ void bar() {
    __builtin_amdgcn_s_barrier();
    asm volatile("" ::: "memory");
}

__device__ __forceinline__ float bf2f(short s) {
    __hip_bfloat16 h;
    *reinterpret_cast<short*>(&h) = s;
    return __bfloat162float(h);
}
__device__ __forceinline__ short f2bf(float f) {
    __hip_bfloat16 h = __float2bfloat16(f);
    return *reinterpret_cast<short*>(&h);
}

// ---------------- bf16 MFMA GEMM: C = A @ Bt^T + epilogue ----------------
// A: [MP][K] bf16 row-major. Bt: [N][K] bf16 (weights pre-transposed).
// Double-buffered gl2lds staging with counted vmcnt (never 0 mid-loop).
// BM in {32,64,128}: 128 -> 2x2 waves of 64x32; 64 -> 2x2 of 32x32; 32 -> 1x4 of 32x16.
// EPI: 1 = bias -> Cf
//      3 = QKV: bias -> Cb (bf16 only)
//      4 = bias+res -> Cf(f32) + Cb(bf16)
//      5 = bias+res -> Cf(f32) AND Cb(bf16) + per-row (sum,sumsq) atomics -> stats
//      6 = epilogue-LN + gelu -> Cb:  v = rinv*acc - mean*rinv*aux[col] + bias[col]
template<int EPI, int BM>
__global__ __launch_bounds__(256)
void mgemm(const __hip_bfloat16* __restrict__ A, const __hip_bfloat16* __restrict__ Bt,
           const float* __restrict__ bias, const float* __restrict__ res,
           float* __restrict__ Cf, __hip_bfloat16* __restrict__ Cb,
           float* __restrict__ stats, const float* __restrict__ aux,
           int M, int N, int K)
{
    constexpr int ACH  = BM * 8;          // A tile 16B-chunks
    constexpr int ABYT = BM * 128;        // A tile bytes
    constexpr int STG  = ABYT + 8192;     // bytes per buffer (A + B)
    constexpr int LPT  = (ACH + 512) / 256; // gl2lds per thread per stage (3/4/6)
    constexpr int NI   = (BM >= 64) ? 2 : 1;
    constexpr int MI   = (BM == 128) ? 4 : 2;
    __shared__ char lds[2 * STG];
    const int tid = threadIdx.x;
    const int bm = blockIdx.y * BM, bn = blockIdx.x << 6;
    const int lane = tid & 63, wv = tid >> 6;
    const int wm = (BM == 128) ? ((wv & 1) << 6) : (BM == 64) ? ((wv & 1) << 5) : 0;
    const int wn = (BM >= 64) ? ((wv >> 1) << 5) : (wv << 4);
    const int fr = lane & 15, kg = lane >> 4;

    int offA[MI][2], offB[NI][2];
    #pragma unroll
    for (int mi = 0; mi < MI; ++mi)
        #pragma unroll
        for (int kk = 0; kk < 2; ++kk) {
            int kb = (kk << 6) + (kg << 4);
            int ra = wm + (mi << 4) + fr;
            offA[mi][kk] = (ra << 7) + (kb ^ ((ra & 7) << 4));
        }
    #pragma unroll
    for (int ni = 0; ni < NI; ++ni)
        #pragma unroll
        for (int kk = 0; kk < 2; ++kk) {
            int kb = (kk << 6) + (kg << 4);
            int rb = wn + (ni << 4) + fr;
            offB[ni][kk] = ABYT + (rb << 7) + (kb ^ ((rb & 7) << 4));
        }

    auto stage = [&](int sb, int k0) {
        char* base = lds + sb * STG;
        #pragma unroll
        for (int c = 0; c < ACH / 256; ++c) {
            int idx = c * 256 + tid;
            int row = idx >> 3, kb = (idx & 7) << 4;
            int gr = bm + row;
            if (BM == 128) gr = gr < M ? gr : (M - 1);   // clamp OOB rows (valid addr)
            gl2lds16((const char*)A + (((size_t)gr * K + k0) << 1) + (kb ^ ((row & 7) << 4)),
                     base + idx * 16);
        }
        #pragma unroll
        for (int c = 0; c < 2; ++c) {
            int idx = c * 256 + tid;
            int row = idx >> 3, kb = (idx & 7) << 4;
            gl2lds16((const char*)Bt + (((size_t)(bn + row) * K + k0) << 1) + (kb ^ ((row & 7) << 4)),
                     base + ABYT + idx * 16);
        }
    };

    f32x4 acc[MI][NI] = {};
    const int NK = K >> 6;
    stage(0, 0);
    for (int ks = 0; ks < NK; ++ks) {
        const int cur = ks & 1;
        if (ks + 1 < NK) { stage(cur ^ 1, (ks + 1) << 6); vmw<LPT>(); }
        else vmw<0>();
        bar();                               // stage ks data visible in LDS
        const char* bp = lds + cur * STG;
        bf16x8 af[MI][2], bf_[NI][2];
        #pragma unroll
        for (int mi = 0; mi < MI; ++mi)
            #pragma unroll
            for (int kk = 0; kk < 2; ++kk)
                af[mi][kk] = *(const bf16x8*)(bp + offA[mi][kk]);
        #pragma unroll
        for (int ni = 0; ni < NI; ++ni)
            #pragma unroll
            for (int kk = 0; kk < 2; ++kk)
                bf_[ni][kk] = *(const bf16x8*)(bp + offB[ni][kk]);
        #pragma unroll
        for (int kk = 0; kk < 2; ++kk)
            #pragma unroll
            for (int mi = 0; mi < MI; ++mi)
                #pragma unroll
                for (int ni = 0; ni < NI; ++ni)
                    acc[mi][ni] = __builtin_amdgcn_mfma_f32_16x16x32_bf16(
                        af[mi][kk], bf_[ni][kk], acc[mi][ni], 0, 0, 0);
        asm volatile("s_waitcnt lgkmcnt(0)" ::: "memory");
        bar();                               // buf[cur] reusable next+1 iter
    }

    const int rb4 = kg << 2;
    float b_[NI], w_[NI];
    #pragma unroll
    for (int ni = 0; ni < NI; ++ni) {
        int col = bn + wn + (ni << 4) + fr;
        b_[ni] = bias[col];
        if (EPI == 6) w_[ni] = aux[col];
    }
    #pragma unroll
    for (int mi = 0; mi < MI; ++mi)
        #pragma unroll
        for (int r = 0; r < 4; ++r) {
            const int row = bm + wm + (mi << 4) + rb4 + r;
            if (row >= M) continue;          // uniform over fr-group
            float mean = 0.f, rinv = 0.f;
            if (EPI == 6) {
                float s0 = stats[row * 2 + 0], s1 = stats[row * 2 + 1];
                mean = s0 * (1.f / 512.f);
                rinv = rsqrtf(s1 * (1.f / 512.f) - mean * mean + EPSLN);
            }
            float vs = 0.f, vq = 0.f;
            #pragma unroll
            for (int ni = 0; ni < NI; ++ni) {
                const int col = bn + wn + (ni << 4) + fr;
                float v = acc[mi][ni][r];
                if (EPI == 6) v = rinv * v - mean * rinv * w_[ni] + b_[ni];
                else v += b_[ni];
                if (EPI == 4 || EPI == 5) v += res[(size_t)row * N + col];
                if (EPI == 6) {
                    float g = 0.5f * v * (1.f + tanhf(0.7978845608028654f * (v + 0.044715f * v * v * v)));
                    Cb[(size_t)row * N + col] = __float2bfloat16(g);
                } else if (EPI == 3) {
                    Cb[(size_t)row * N + col] = __float2bfloat16(v);
                } else if (EPI == 4) {
                    Cf[(size_t)row * N + col] = v;
                    Cb[(size_t)row * N + col] = __float2bfloat16(v);
                } else if (EPI == 5) {
                    Cf[(size_t)row * N + col] = v;
                    Cb[(size_t)row * N + col] = __float2bfloat16(v);
                    vs += v; vq += v * v;
                } else {
                    Cf[(size_t)row * N + col] = v;
                }
            }
            if (EPI == 5) {
                #pragma unroll
                for (int m2 = 1; m2 < 16; m2 <<= 1) {
                    vs += __shfl_xor(vs, m2);
                    vq += __shfl_xor(vq, m2);
                }
                if (fr == 0) {
                    atomicAdd(&stats[row * 2 + 0], vs);
                    atomicAdd(&stats[row * 2 + 1], vq);
                }
            }
        }
}

// ---------------- halting GEMM: z[row][0:2] += tanh(chi@Wh1+bh1) @ Wh2 ----------------
// Plain bf16. N=K=512 fixed. BM=32, double-buffered.
__global__ __launch_bounds__(256)
void halt_gemm(const __hip_bfloat16* __restrict__ Ahp, const __hip_bfloat16* __restrict__ Bhp,
               const float* __restrict__ bh1, const float* __restrict__ Wh2,
               float* __restrict__ z, int M)
{
    constexpr int STG = 12288;   // Ah 4K @0, Bh 8K @4096
    __shared__ char lds[2 * STG];
    const int tid = threadIdx.x;
    const int bm = blockIdx.y << 5, bn = blockIdx.x << 6;
    const int lane = tid & 63, wv = tid >> 6;
    const int wn = wv << 4;
    const int fr = lane & 15, kg = lane >> 4;

    int offA[2][2], offB[2];
    #pragma unroll
    for (int mi = 0; mi < 2; ++mi)
        #pragma unroll
        for (int kk = 0; kk < 2; ++kk) {
            int kb = (kk << 6) + (kg << 4);
            int ra = (mi << 4) + fr;
            offA[mi][kk] = (ra << 7) + (kb ^ ((ra & 7) << 4));
        }
    #pragma unroll
    for (int kk = 0; kk < 2; ++kk) {
        int kb = (kk << 6) + (kg << 4);
        int rb = wn + fr;
        offB[kk] = 4096 + (rb << 7) + (kb ^ ((rb & 7) << 4));
    }

    auto stage = [&](int sb, int k0) {
        char* base = lds + sb * STG;
        {
            int row = tid >> 3, kb = (tid & 7) << 4;
            int swz = kb ^ ((row & 7) << 4);
            size_t aoff = (((size_t)(bm + row) * 512 + k0) << 1) + swz;
            gl2lds16((const char*)Ahp + aoff, base + tid * 16);
        }
        #pragma unroll
        for (int c = 0; c < 2; ++c) {
            int idx = c * 256 + tid;
            int row = idx >> 3, kb = (idx & 7) << 4;
            int swz = kb ^ ((row & 7) << 4);
            size_t boff = (((size_t)(bn + row) * 512 + k0) << 1) + swz;
            gl2lds16((const char*)Bhp + boff, base + 4096 + idx * 16);
        }
    };

    f32x4 acc[2] = {};
    stage(0, 0);
    for (int ks = 0; ks < 8; ++ks) {
        const int cur = ks & 1;
        if (ks < 7) { stage(cur ^ 1, (ks + 1) << 6); vmw<3>(); }
        else vmw<0>();
        bar();
        const char* bp = lds + cur * STG;
        bf16x8 ah[2][2], bh_[2];
        #pragma unroll
        for (int mi = 0; mi < 2; ++mi)
            #pragma unroll
            for (int kk = 0; kk < 2; ++kk)
                ah[mi][kk] = *(const bf16x8*)(bp + offA[mi][kk]);
        #pragma unroll
        for (int kk = 0; kk < 2; ++kk)
            bh_[kk] = *(const bf16x8*)(bp + offB[kk]);
        #pragma unroll
        for (int kk = 0; kk < 2; ++kk)
            #pragma unroll
            for (int mi = 0; mi < 2; ++mi)
                acc[mi] = __builtin_amdgcn_mfma_f32_16x16x32_bf16(ah[mi][kk], bh_[kk], acc[mi], 0, 0, 0);
        asm volatile("s_waitcnt lgkmcnt(0)" ::: "memory");
        bar();
    }

    const int col = bn + wn + fr;
    const float b_ = bh1[col];
    const float w0_ = Wh2[col * 2 + 0];
    const float w1_ = Wh2[col * 2 + 1];
    #pragma unroll
    for (int mi = 0; mi < 2; ++mi)
        #pragma unroll
        for (int r = 0; r < 4; ++r) {
            float v = tanhf(acc[mi][r] + b_);
            float p0 = v * w0_;
            float p1 = v * w1_;
            #pragma unroll
            for (int m2 = 1; m2 < 16; m2 <<= 1) {
                p0 += __shfl_xor(p0, m2);
                p1 += __shfl_xor(p1, m2);
            }
            if (fr == 0) {
                int row = bm + (mi << 4) + (kg << 2) + r;
                if (row < M) {
                    atomicAdd(&z[row * 2 + 0], p0);
                    atomicAdd(&z[row * 2 + 1], p1);
                }
            }
        }
}

// ---------------- MFMA attention ----------------
// grid (5 q-chunks, 8 heads, 16 batch), 256 threads. All inputs read from bf16 qkvb.
// Distributed in-register ONE-BARRIER softmax: each wave publishes (m_w, sum_w=
// sum exp(s-m_w)); after one barrier, gm/tot combined per row. P aliases dead KT.
#define KT_BASE 0          // [144][128B] XOR-swizzled K (B-layout)   18432
#define P_BASE  0          // [32][336B] bf16 softmax — ALIASES KT    10752
#define VT_BASE 18432      // [64][384B] XOR-swizzled V^T             24576
#define QC_BASE 43008      // [32][72] bf16 q+cb (stride 144B)         4608
#define R_BASE  47616      // [32][8] f32 rel logits                   1024
#define WM_BASE 48640      // [4][32] f32 per-wave row max              512
#define WS_BASE 49152      // [4][32] f32 per-wave row sum              512
__global__ __launch_bounds__(256)
void attn_mfma(const __hip_bfloat16* __restrict__ qkvb,
               const float* __restrict__ rk7, const float* __restrict__ cbias,
               const float* __restrict__ rbias, __hip_bfloat16* __restrict__ aout)
{
    __shared__ char lds[49664];
    const int tid = threadIdx.x;
    const int chunk = blockIdx.x, hh = blockIdx.y, b = blockIdx.z;
    const int q0 = chunk << 5;
    const int lane = tid & 63, wv = tid >> 6;
    const int fr = lane & 15, kg = lane >> 4;
    const size_t qrow0 = (size_t)b * Sc;
    const short* qs = (const short*)qkvb;

    // phase 0: zero VT (full 24576B) + Kt pad rows 129..143
    {
        f32x4 zz = {};
        #pragma unroll
        for (int i = 0; i < 6; ++i)
            *(f32x4*)(lds + VT_BASE + (i * 256 + tid) * 16) = zz;
        if (tid < 120)
            *(f32x4*)(lds + KT_BASE + 129 * 128 + tid * 16) = zz;
    }
    __syncthreads();

    // stage Kt (rows 0..128) via global_load_lds, XOR pre-swizzled source
    #pragma unroll
    for (int i = 0; i < 5; ++i) {
        int idx = i * 256 + tid;
        if (idx < 1152) {
            int row = idx >> 3, ch = idx & 7;
            if (row <= 128) {
                const char* src = (const char*)qkvb +
                    (((qrow0 + row) * 1536 + 512 + (size_t)hh * 64) << 1) + ((ch ^ (row & 7)) << 4);
                gl2lds16(src, lds + KT_BASE + idx * 16);
            }
        }
    }
    // stage V^T: swizzled scatter writes (conflict-free by key=(g^j))
    #pragma unroll
    for (int i = 0; i < 5; ++i) {
        int idx = i * 256 + tid;
        if (idx < 1032) {                    // 129 T-slots x 8 d-groups
            int T = idx >> 3, g = idx & 7;
            bf16x8 v = *(const bf16x8*)(qs + (qrow0 + T) * 1536 + 1024 + hh * 64 + g * 8);
            #pragma unroll
            for (int j = 0; j < 8; ++j) {
                int row = g * 8 + j;
                int key = (g ^ j) & 7;
                *(short*)(lds + VT_BASE + row * 384 + ((T * 2) ^ (key << 4))) = v[j];
            }
        }
    }
    // stage Qc = bf16(q + content_bias): 256 threads = 32 rows x 8 groups
    {
        int row = tid >> 3, g = tid & 7;
        bf16x8 q8 = *(const bf16x8*)(qs + (qrow0 + q0 + row) * 1536 + hh * 64 + g * 8);
        const float* cb = cbias + hh * 64 + g * 8;
        bf16x8 o8;
        #pragma unroll
        for (int j = 0; j < 8; ++j)
            o8[j] = f2bf(bf2f(q8[j]) + cb[j]);
        *(bf16x8*)(lds + QC_BASE + row * 144 + g * 16) = o8;
    }
    // R[row][c] = (q + rbias) . rk7[c], bf16 q loads vectorized
    if (tid < 224) {
        int row = tid / 7, c = tid % 7;
        const short* qp = qs + (qrow0 + q0 + row) * 1536 + hh * 64;
        const float* rp  = rk7 + c * 512 + hh * 64;
        const float* rbp = rbias + hh * 64;
        float a = 0.f;
        #pragma unroll
        for (int g = 0; g < 8; ++g) {
            bf16x8 q8 = *(const bf16x8*)(qp + g * 8);
            #pragma unroll
            for (int j = 0; j < 8; ++j)
                a += (bf2f(q8[j]) + rbp[g * 8 + j]) * rp[g * 8 + j];
        }
        *(float*)(lds + R_BASE + (row * 8 + c) * 4) = a;
    }
    __syncthreads();

    // QK^T: 9 N-tiles over 4 waves
    f32x4 acc[2][3] = {};
    __builtin_amdgcn_s_setprio(1);
    #pragma unroll
    for (int ni = 0; ni < 3; ++ni) {
        int nt = wv + ni * 4;
        if (nt > 8) continue;
        #pragma unroll
        for (int mt = 0; mt < 2; ++mt)
            #pragma unroll
            for (int ks = 0; ks < 2; ++ks) {
                bf16x8 a = *(const bf16x8*)(lds + QC_BASE + (mt * 16 + fr) * 144 + ks * 64 + kg * 16);
                int rowb = nt * 16 + fr;
                bf16x8 bb = *(const bf16x8*)(lds + KT_BASE + rowb * 128 +
                                             ((ks * 64 + kg * 16) ^ ((rowb & 7) << 4)));
                acc[mt][ni] = __builtin_amdgcn_mfma_f32_16x16x32_bf16(a, bb, acc[mt][ni], 0, 0, 0);
            }
    }
    __builtin_amdgcn_s_setprio(0);

    // s = (cl + rl)*scale, masked — in registers (overwrite acc)
    #pragma unroll
    for (int ni = 0; ni < 3; ++ni) {
        int nt = wv + ni * 4;
        int col = nt * 16 + fr;
        #pragma unroll
        for (int mt = 0; mt < 2; ++mt)
            #pragma unroll
            for (int r = 0; r < 4; ++r) {
                int row = mt * 16 + kg * 4 + r;
                float sv = -1e30f;
                if (nt <= 8 && col <= 128) {
                    int delta = q0 + row - col;
                    int c = delta >= 3 ? 3 : (delta <= -3 ? 4 : (delta < 0 ? delta + 7 : delta));
                    float rl = *(const float*)(lds + R_BASE + (row * 8 + c) * 4);
                    sv = (acc[mt][ni][r] + rl) * 0.125f;
                }
                acc[mt][ni][r] = sv;
            }
    }

    // per-wave max + per-wave exp-sum (relative to own max), ONE barrier
    float m_[2][4], su[2][4];
    #pragma unroll
    for (int mt = 0; mt < 2; ++mt)
        #pragma unroll
        for (int r = 0; r < 4; ++r) {
            float m = fmaxf(fmaxf(acc[mt][0][r], acc[mt][1][r]), acc[mt][2][r]);
            #pragma unroll
            for (int b2 = 1; b2 < 16; b2 <<= 1) m = fmaxf(m, __shfl_xor(m, b2));
            m_[mt][r] = m;
            su[mt][r] = 0.f;
        }
    #pragma unroll
    for (int ni = 0; ni < 3; ++ni)
        #pragma unroll
        for (int mt = 0; mt < 2; ++mt)
            #pragma unroll
            for (int r = 0; r < 4; ++r) {
                float s = acc[mt][ni][r];
                float e = (s > -1e29f) ? expf(s - m_[mt][r]) : 0.f;
                acc[mt][ni][r] = e;
                su[mt][r] += e;
            }
    #pragma unroll
    for (int mt = 0; mt < 2; ++mt)
        #pragma unroll
        for (int r = 0; r < 4; ++r) {
            float s = su[mt][r];
            #pragma unroll
            for (int b2 = 1; b2 < 16; b2 <<= 1) s += __shfl_xor(s, b2);
            su[mt][r] = s;
        }
    if (fr == 0) {
        float* wm = (float*)(lds + WM_BASE) + (wv << 5);
        float* ws = (float*)(lds + WS_BASE) + (wv << 5);
        #pragma unroll
        for (int mt = 0; mt < 2; ++mt)
            #pragma unroll
            for (int r = 0; r < 4; ++r) {
                wm[mt * 16 + (kg << 2) + r] = m_[mt][r];
                ws[mt * 16 + (kg << 2) + r] = su[mt][r];
            }
    }
    __syncthreads();                        // bar1: softmax partials ready; KT dead

    // zero P cols 144..159 (32 rows x 32B), safe after bar1
    if (tid < 128) {
        int row = tid >> 2;
        *(double*)(lds + P_BASE + row * 336 + 288 + (tid & 3) * 8) = 0.0;
    }

    // combine: gm = max over waves; tot = sum ws_w * exp(wm_w - gm);
    // this wave's scale = exp(m_self - gm)/tot
    const float* wmv = (const float*)(lds + WM_BASE);
    const float* wsv = (const float*)(lds + WS_BASE);
    float fac[2][4];
    #pragma unroll
    for (int mt = 0; mt < 2; ++mt)
        #pragma unroll
        for (int r = 0; r < 4; ++r) {
            int row = mt * 16 + (kg << 2) + r;
            float m0 = wmv[row],      m1 = wmv[32 + row];
            float m2 = wmv[64 + row], m3 = wmv[96 + row];
            float gm = fmaxf(fmaxf(m0, m1), fmaxf(m2, m3));
            float tot = wsv[row] * expf(m0 - gm) + wsv[32 + row] * expf(m1 - gm)
                      + wsv[64 + row] * expf(m2 - gm) + wsv[96 + row] * expf(m3 - gm);
            fac[mt][r] = expf(m_[mt][r] - gm) / tot;
        }
    // P write (bf16) into aliased KT region
    #pragma unroll
    for (int ni = 0; ni < 3; ++ni) {
        int nt = wv + ni * 4;
        if (nt > 8) continue;
        int col = nt * 16 + fr;
        #pragma unroll
        for (int mt = 0; mt < 2; ++mt)
            #pragma unroll
            for (int r = 0; r < 4; ++r) {
                int row = mt * 16 + (kg << 2) + r;
                *(short*)(lds + P_BASE + row * 336 + col * 2) =
                    f2bf(acc[mt][ni][r] * fac[mt][r]);
            }
    }
    __syncthreads();                        // bar2: P ready

    // PV: wave owns 16 output dims; V^T read with matching XOR swizzle
    f32x4 acc2[2] = {};
    const int rowv = wv * 16 + fr;
    const int keyv = ((rowv >> 3) ^ rowv) & 7;
    __builtin_amdgcn_s_setprio(1);
    #pragma unroll
    for (int mt = 0; mt < 2; ++mt)
        #pragma unroll
        for (int ks = 0; ks < 5; ++ks) {
            bf16x8 a  = *(const bf16x8*)(lds + P_BASE + (mt * 16 + fr) * 336 + ks * 64 + kg * 16);
            bf16x8 bb = *(const bf16x8*)(lds + VT_BASE + rowv * 384 +
                                         ((ks * 64 + kg * 16) ^ (keyv << 4)));
            acc2[mt] = __builtin_amdgcn_mfma_f32_16x16x32_bf16(a, bb, acc2[mt], 0, 0, 0);
        }
    __builtin_amdgcn_s_setprio(0);
    #pragma unroll
    for (int mt = 0; mt < 2; ++mt)
        #pragma unroll
        for (int r = 0; r < 4; ++r) {
            int t = q0 + mt * 16 + kg * 4 + r;
            if (t <= 128)
                aout[(qrow0 + t) * 512 + hh * 64 + wv * 16 + fr] = __float2bfloat16(acc2[mt][r]);
        }
}

// ---------------- ACT bookkeeping + LN(curr) + blend + h_out ----------------
// 4 rows per block, one 64-lane wave per row; no LDS, no syncthreads.
__global__ __launch_bounds__(256)
void haltblend(const float* __restrict__ curr, const float* __restrict__ s,
               const float* __restrict__ o, float* __restrict__ zbuf,
               float* __restrict__ lanh, float* __restrict__ lah,
               float* __restrict__ h, __hip_bfloat16* __restrict__ hb,
               float* __restrict__ hout, float* __restrict__ stats)
{
    const int row = (blockIdx.x << 2) + (threadIdx.x >> 6);
    const int lane = threadIdx.x & 63;

    float z0 = zbuf[row * 2 + 0] + 2.f;
    float z1 = zbuf[row * 2 + 1] - 2.f;
    float mxz = fmaxf(z0, z1);
    float lse = mxz + logf(expf(z0 - mxz) + expf(z1 - mxz));
    float lg0 = z0 - lse, lg1 = z1 - lse;
    float ln_ = lanh[row], la_ = lah[row];
    float lhalt = ln_ + lg1;
    float hl = expf(la_);            // PRE-update lah
    float ph = expf(lhalt);

    const size_t rbase = (size_t)row * 512;
    const int c0 = lane << 3;
    f32x4 x0 = *(const f32x4*)(curr + rbase + c0);
    f32x4 x1 = *(const f32x4*)(curr + rbase + c0 + 4);
    float sum = (x0[0] + x0[1]) + (x0[2] + x0[3]) + (x1[0] + x1[1]) + (x1[2] + x1[3]);
    float sq  = (x0[0] * x0[0] + x0[1] * x0[1]) + (x0[2] * x0[2] + x0[3] * x0[3])
              + (x1[0] * x1[0] + x1[1] * x1[1]) + (x1[2] * x1[2] + x1[3] * x1[3]);
    #pragma unroll
    for (int m2 = 1; m2 < 64; m2 <<= 1) { sum += __shfl_xor(sum, m2); sq += __shfl_xor(sq, m2); }
    float mean = sum * (1.f / 512.f);
    float inv = rsqrtf(sq * (1.f / 512.f) - mean * mean + EPSLN);

    if (lane == 0) {
        lanh[row] = ln_ + lg0;
        float m3 = fmaxf(la_, lhalt);
        lah[row] = m3 + logf(expf(la_ - m3) + expf(lhalt - m3));
        zbuf[row * 2 + 0] = 0.f;
        zbuf[row * 2 + 1] = 0.f;
        stats[row * 2 + 0] = 0.f;    // reset LN stats for next iteration's Wo epilogue
        stats[row * 2 + 1] = 0.f;
    }

    f32x4 sv0 = *(const f32x4*)(s + c0), sv1 = *(const f32x4*)(s + c0 + 4);
    f32x4 ov0 = *(const f32x4*)(o + c0), ov1 = *(const f32x4*)(o + c0 + 4);
    f32x4 hv0 = *(f32x4*)(h + rbase + c0), hv1 = *(f32x4*)(h + rbase + c0 + 4);
    f32x4 ho0 = *(f32x4*)(hout + rbase + c0), ho1 = *(f32x4*)(hout + rbase + c0 + 4);
    u16x4 hb0, hb1;
    #pragma unroll
    for (int e = 0; e < 4; ++e) {
        float cl = (x0[e] - mean) * inv * sv0[e] + ov0[e];
        float hn = hl * hv0[e] + (1.f - hl) * cl;
        hv0[e] = hn;
        __hip_bfloat16 bb = __float2bfloat16(hn);
        hb0[e] = *reinterpret_cast<unsigned short*>(&bb);
        ho0[e] += ph * cl;
    }
    #pragma unroll
    for (int e = 0; e < 4; ++e) {
        float cl = (x1[e] - mean) * inv * sv1[e] + ov1[e];
        float hn = hl * hv1[e] + (1.f - hl) * cl;
        hv1[e] = hn;
        __hip_bfloat16 bb = __float2bfloat16(hn);
        hb1[e] = *reinterpret_cast<unsigned short*>(&bb);
        ho1[e] += ph * cl;
    }
    *(f32x4*)(h + rbase + c0) = hv0;
    *(f32x4*)(h + rbase + c0 + 4) = hv1;
    *(u16x4*)(reinterpret_cast<unsigned short*>(hb) + rbase + c0) = hb0;
    *(u16x4*)(reinterpret_cast<unsigned short*>(hb) + rbase + c0 + 4) = hb1;
    *(f32x4*)(hout + rbase + c0) = ho0;
    *(f32x4*)(hout + rbase + c0 + 4) = ho1;
}

// ---------------- setup kernels ----------------
__global__ __launch_bounds__(256)
void emb_kernel(const float* __restrict__ x, const float* __restrict__ We,
                const float* __restrict__ eos, const float* __restrict__ s,
                const float* __restrict__ o, float* __restrict__ h,
                __hip_bfloat16* __restrict__ hb)
{
    int row = blockIdx.x, tid = threadIdx.x;
    int b = row / Sc, t = row % Sc;
    __shared__ float xs[64];
    if (t != 128 && tid < 64) xs[tid] = x[((size_t)b * 128 + t) * 64 + tid];
    __syncthreads();
    float v0, v1;
    if (t == 128) {
        v0 = eos[tid]; v1 = eos[tid + 256];
    } else {
        v0 = 0.f; v1 = 0.f;
        #pragma unroll 8
        for (int k = 0; k < 64; ++k) {
            float xv = xs[k];
            v0 = fmaf(xv, We[k * 512 + tid], v0);
            v1 = fmaf(xv, We[k * 512 + tid + 256], v1);
        }
    }
    float sum = v0 + v1, sq = v0 * v0 + v1 * v1;
    #pragma unroll
    for (int m2 = 1; m2 < 64; m2 <<= 1) { sum += __shfl_xor(sum, m2); sq += __shfl_xor(sq, m2); }
    __shared__ float ssum[4], ssq[4];
    if ((tid & 63) == 0) { ssum[tid >> 6] = sum; ssq[tid >> 6] = sq; }
    __syncthreads();
    float tot = ssum[0] + ssum[1] + ssum[2] + ssum[3];
    float totq = ssq[0] + ssq[1] + ssq[2] + ssq[3];
    float mean = tot * (1.f / 512.f);
    float inv = rsqrtf(totq * (1.f / 512.f) - mean * mean + EPSLN);
    float h0 = (v0 - mean) * inv * s[tid] + o[tid];
    float h1 = (v1 - mean) * inv * s[tid + 256] + o[tid + 256];
    h[(size_t)row * 512 + tid] = h0;
    h[(size_t)row * 512 + tid + 256] = h1;
    hb[(size_t)row * 512 + tid] = __float2bfloat16(h0);
    hb[(size_t)row * 512 + tid + 256] = __float2bfloat16(h1);
}

__global__ __launch_bounds__(256)
void rk7_kernel(const float* __restrict__ pos, const float* __restrict__ Wk,
                const float* __restrict__ bk, float* __restrict__ rk7)
{
    int c = blockIdx.x, tid = threadIdx.x;
    __shared__ float ps[512];
    ps[tid] = pos[c * 512 + tid];
    ps[tid + 256] = pos[c * 512 + tid + 256];
    __syncthreads();
    float a0 = bk[tid], a1 = bk[tid + 256];
    for (int k = 0; k < 512; ++k) {
        float pv = ps[k];
        a0 = fmaf(pv, Wk[(size_t)k * 512 + tid], a0);
        a1 = fmaf(pv, Wk[(size_t)k * 512 + tid + 256], a1);
    }
    rk7[c * 512 + tid] = a0;
    rk7[c * 512 + tid + 256] = a1;
}

__global__ __launch_bounds__(256)
void pack_qkvT(const float* __restrict__ Wq, const float* __restrict__ Wk,
               const float* __restrict__ Wv, __hip_bfloat16* __restrict__ Wt)
{
    int idx = blockIdx.x * 256 + threadIdx.x;
    if (idx >= 1536 * 512) return;
    int n = idx >> 9, k = idx & 511;
    const float* src = (n < 512) ? Wq : (n < 1024) ? Wk : Wv;
    int nc = n & 511;
    Wt[idx] = __float2bfloat16(src[(size_t)k * 512 + nc]);
}

__global__ __launch_bounds__(256)
void transposeT(const float* __restrict__ W, __hip_bfloat16* __restrict__ Wt, int K, int N)
{
    int idx = blockIdx.x * 256 + threadIdx.x;
    if (idx >= K * N) return;
    int n = idx / K, k = idx - n * K;
    Wt[idx] = __float2bfloat16(W[(size_t)k * N + n]);
}

// Wt[n][k] = bf16(W[k][n] * s[k])   (fold LN scale into W1)
__global__ __launch_bounds__(256)
void transposeT_scale(const float* __restrict__ W, const float* __restrict__ s,
                      __hip_bfloat16* __restrict__ Wt, int K, int N)
{
    int idx = blockIdx.x * 256 + threadIdx.x;
    if (idx >= K * N) return;
    int n = idx / K, k = idx - n * K;
    Wt[idx] = __float2bfloat16(W[(size_t)k * N + n] * s[k]);
}

// w1sum[n] = sum_k s[k]*W[k][n];  b1f[n] = b[n] + sum_k o[k]*W[k][n]
__global__ __launch_bounds__(256)
void fold_w1(const float* __restrict__ W, const float* __restrict__ s,
             const float* __restrict__ o, const float* __restrict__ b,
             float* __restrict__ w1sum, float* __restrict__ b1f, int K, int N)
{
    int n = blockIdx.x * 256 + threadIdx.x;
    if (n >= N) return;
    float ws = 0.f, bo_ = b[n];
    for (int k = 0; k < K; ++k) {
        float w = W[(size_t)k * N + n];
        ws = fmaf(s[k], w, ws);
        bo_ = fmaf(o[k], w, bo_);
    }
    w1sum[n] = ws;
    b1f[n] = bo_;
}

__global__ __launch_bounds__(256)
void pack_bias(const float* __restrict__ bq, const float* __restrict__ bk,
               const float* __restrict__ bv, float* __restrict__ bqkv)
{
    int idx = blockIdx.x * 256 + threadIdx.x;
    if (idx < 1536)
        bqkv[idx] = (idx < 512) ? bq[idx] : (idx < 1024) ? bk[idx - 512] : bv[idx - 1024];
}

__global__ __launch_bounds__(256)
void init_kernel(float* __restrict__ lanh, float* __restrict__ lah,
                 float* __restrict__ zbuf, float* __restrict__ stats)
{
    int idx = blockIdx.x * 256 + threadIdx.x;
    if (idx < Mc) {
        lanh[idx] = 0.f; lah[idx] = -64.f;
        zbuf[idx * 2 + 0] = 0.f; zbuf[idx * 2 + 1] = 0.f;
    }
    if (idx < MP) {
        stats[idx * 2 + 0] = 0.f; stats[idx * 2 + 1] = 0.f;
    }
}

// ---------------- host launcher ----------------
extern "C" void kernel_launch(void* const* d_in, const int* in_sizes, int n_in,
                              void* d_out, int out_size, void* d_ws, size_t ws_size,
                              hipStream_t stream)
{
    const float* x     = (const float*)d_in[0];
    const float* We    = (const float*)d_in[1];
    const float* eos   = (const float*)d_in[2];
    const float* Wq    = (const float*)d_in[3];
    const float* bq    = (const float*)d_in[4];
    const float* Wk    = (const float*)d_in[5];
    const float* bk    = (const float*)d_in[6];
    const float* Wv    = (const float*)d_in[7];
    const float* bv    = (const float*)d_in[8];
    const float* Wo    = (const float*)d_in[9];
    const float* bo    = (const float*)d_in[10];
    const float* cbias = (const float*)d_in[11];
    const float* rbias = (const float*)d_in[12];
    const float* pos   = (const float*)d_in[13];
    const float* ln2s  = (const float*)d_in[14];
    const float* ln2o  = (const float*)d_in[15];
    const float* lnos  = (const float*)d_in[16];
    const float* lnoo  = (const float*)d_in[17];
    const float* W1    = (const float*)d_in[18];
    const float* b1    = (const float*)d_in[19];
    const float* W2    = (const float*)d_in[20];
    const float* b2    = (const float*)d_in[21];
    const float* Wh1   = (const float*)d_in[22];
    const float* bh1   = (const float*)d_in[23];
    const float* Wh2   = (const float*)d_in[24];
    (void)in_sizes; (void)n_in; (void)ws_size;

    char* wp = (char*)d_ws;
    auto alloc = [&](size_t bytes) { char* p = wp; wp += (bytes + 255) & ~(size_t)255; return p; };
    float*          h     = (float*)alloc((size_t)MP * 512 * 4);
    __hip_bfloat16* hb    = (__hip_bfloat16*)alloc((size_t)MP * 512 * 2);
    __hip_bfloat16* qkvb  = (__hip_bfloat16*)alloc((size_t)MP * 1536 * 2);
    __hip_bfloat16* abufb = (__hip_bfloat16*)alloc((size_t)MP * 512 * 2);
    float*          hmid  = (float*)alloc((size_t)MP * 512 * 4);
    __hip_bfloat16* hmidb = (__hip_bfloat16*)alloc((size_t)MP * 512 * 2);
    __hip_bfloat16* g1b   = (__hip_bfloat16*)alloc((size_t)MP * 1024 * 2);
    float*          curr  = (float*)alloc((size_t)MP * 512 * 4);
    __hip_bfloat16* chi   = (__hip_bfloat16*)alloc((size_t)MP * 512 * 2);
    __hip_bfloat16* WqkvT = (__hip_bfloat16*)alloc((size_t)1536 * 512 * 2);
    __hip_bfloat16* WoT   = (__hip_bfloat16*)alloc((size_t)512 * 512 * 2);
    __hip_bfloat16* W1T   = (__hip_bfloat16*)alloc((size_t)1024 * 512 * 2);
    __hip_bfloat16* W2T   = (__hip_bfloat16*)alloc((size_t)512 * 1024 * 2);
    __hip_bfloat16* Wh1Th = (__hip_bfloat16*)alloc((size_t)512 * 512 * 2);
    float*          bqkv  = (float*)alloc(1536 * 4);
    float*          w1sum = (float*)alloc(1024 * 4);
    float*          b1f   = (float*)alloc(1024 * 4);
    float*          rk7   = (float*)alloc(7 * 512 * 4);
    float*          lanh  = (float*)alloc(Mc * 4);
    float*          lah   = (float*)alloc(Mc * 4);
    float*          zbuf  = (float*)alloc((size_t)Mc * 2 * 4);
    float*          stats = (float*)alloc((size_t)MP * 2 * 4);
    float* hout = (float*)d_out;

    hipMemsetAsync(d_out, 0, (size_t)out_size * sizeof(float), stream);
    init_kernel<<<(MP + 255) / 256, 256, 0, stream>>>(lanh, lah, zbuf, stats);
    pack_qkvT<<<(1536 * 512 + 255) / 256, 256, 0, stream>>>(Wq, Wk, Wv, WqkvT);
    transposeT<<<(512 * 512 + 255) / 256, 256, 0, stream>>>(Wo, WoT, 512, 512);
    transposeT_scale<<<(512 * 1024 + 255) / 256, 256, 0, stream>>>(W1, ln2s, W1T, 512, 1024);
    fold_w1<<<4, 256, 0, stream>>>(W1, ln2s, ln2o, b1, w1sum, b1f, 512, 1024);
    transposeT<<<(1024 * 512 + 255) / 256, 256, 0, stream>>>(W2, W2T, 1024, 512);
    transposeT<<<(512 * 512 + 255) / 256, 256, 0, stream>>>(Wh1, Wh1Th, 512, 512);
    pack_bias<<<(1536 + 255) / 256, 256, 0, stream>>>(bq, bk, bv, bqkv);
    rk7_kernel<<<7, 256, 0, stream>>>(pos, Wk, bk, rk7);
    emb_kernel<<<Mc, 256, 0, stream>>>(x, We, eos, lnos, lnoo, h, hb);

    for (int it = 0; it < ITERS; ++it) {
        mgemm<3, 128><<<dim3(24, 17), 256, 0, stream>>>(
            hb, WqkvT, bqkv, nullptr, nullptr, qkvb, nullptr, nullptr, Mc, 1536, 512);
        attn_mfma<<<dim3(5, 8, 16), 256, 0, stream>>>(qkvb, rk7, cbias, rbias, abufb);
        mgemm<5, 32><<<dim3(8, 66), 256, 0, stream>>>(
            abufb, WoT, bo, h, hmid, hmidb, stats, nullptr, Mc, 512, 512);
        mgemm<6, 64><<<dim3(16, 33), 256, 0, stream>>>(
            hmidb, W1T, b1f, nullptr, nullptr, g1b, stats, w1sum, Mc, 1024, 512);
        mgemm<4, 32><<<dim3(8, 66), 256, 0, stream>>>(
            g1b, W2T, b2, hmid, curr, chi, nullptr, nullptr, Mc, 512, 1024);
        halt_gemm<<<dim3(8, 66), 256, 0, stream>>>(chi, Wh1Th, bh1, Wh2, zbuf, Mc);
        haltblend<<<Mc / 4, 256, 0, stream>>>(curr, lnos, lnoo, zbuf, lanh, lah, h, hb, hout, stats);
    }
}

// Round 12
// 11037.778 us; speedup vs baseline: 1.0073x; 1.0073x over previous
//
#include <hip/hip_runtime.h>
#include <hip/hip_bf16.h>
#include <cstdint>
#include <cmath>

#define EPSLN 1e-5f

typedef __attribute__((ext_vector_type(8))) short bf16x8;
typedef __attribute__((ext_vector_type(4))) float f32x4;
typedef __attribute__((ext_vector_type(4))) unsigned short u16x4;

constexpr int Bc = 16;
constexpr int Sc = 129;          // T+1
constexpr int Mc = Bc * Sc;      // 2064 rows (real)
constexpr int MP = 2112;         // padded rows = 33*64 = 66*32
constexpr int ITERS = 127;       // T-1

__device__ __forceinline__ void gl2lds16(const void* g, void* l) {
    __builtin_amdgcn_global_load_lds(
        (const __attribute__((address_space(1))) unsigned int*)g,
        (__attribute__((address_space(3))) unsigned int*)l, 16, 0, 0);
}

template<int N> __device__ __forceinline__ void vmw() {
    if constexpr (N == 0) asm volatile("s_waitcnt vmcnt(0)" ::: "memory");
    else if constexpr (N == 3) asm volatile("s_waitcnt vmcnt(3)" ::: "memory");
    else if constexpr (N == 4) asm volatile("s_waitcnt vmcnt(4)" ::: "memory");
    else if constexpr (N == 6) asm volatile("s_waitcnt vmcnt(6)" ::: "memory");
}

__device__ __forceinline__ void bar() {
    __builtin_amdgcn_s_barrier();
    asm volatile("" ::: "memory");
}

__device__ __forceinline__ float bf2f(short s) {
    __hip_bfloat16 h;
    *reinterpret_cast<short*>(&h) = s;
    return __bfloat162float(h);
}
__device__ __forceinline__ short f2bf(float f) {
    __hip_bfloat16 h = __float2bfloat16(f);
    return *reinterpret_cast<short*>(&h);
}

// ---------------- bf16 MFMA GEMM: C = A @ Bt^T + epilogue ----------------
// A: [MP][K] bf16 row-major. Bt: [N][K] bf16 (weights pre-transposed).
// Double-buffered gl2lds staging with counted vmcnt (never 0 mid-loop).
// BM in {32,64}: 64 -> 2x2 waves of 32x32; 32 -> 1x4 waves of 32x16.
// EPI: 1 = bias -> Cf
//      3 = QKV: bias -> Cb (bf16 only)
//      4 = bias+res -> Cf(f32) + Cb(bf16)
//      5 = bias+res -> Cf(f32) AND Cb(bf16) + per-row (sum,sumsq) atomics -> stats
//      6 = epilogue-LN + gelu -> Cb:  v = rinv*acc - mean*rinv*aux[col] + bias[col]
template<int EPI, int BM>
__global__ __launch_bounds__(256)
void mgemm(const __hip_bfloat16* __restrict__ A, const __hip_bfloat16* __restrict__ Bt,
           const float* __restrict__ bias, const float* __restrict__ res,
           float* __restrict__ Cf, __hip_bfloat16* __restrict__ Cb,
           float* __restrict__ stats, const float* __restrict__ aux,
           int M, int N, int K)
{
    constexpr int ACH  = BM * 8;          // A tile 16B-chunks
    constexpr int ABYT = BM * 128;        // A tile bytes
    constexpr int STG  = ABYT + 8192;     // bytes per buffer (A + B)
    constexpr int LPT  = (ACH + 512) / 256; // gl2lds per thread per stage (4 or 3)
    constexpr int NI   = (BM == 64) ? 2 : 1;
    __shared__ char lds[2 * STG];
    const int tid = threadIdx.x;
    const int bm = blockIdx.y * BM, bn = blockIdx.x << 6;
    const int lane = tid & 63, wv = tid >> 6;
    const int wm = (BM == 64) ? ((wv & 1) << 5) : 0;
    const int wn = (BM == 64) ? ((wv >> 1) << 5) : (wv << 4);
    const int fr = lane & 15, kg = lane >> 4;

    int offA[2][2], offB[2][2];
    #pragma unroll
    for (int mi = 0; mi < 2; ++mi)
        #pragma unroll
        for (int kk = 0; kk < 2; ++kk) {
            int kb = (kk << 6) + (kg << 4);
            int ra = wm + (mi << 4) + fr;
            offA[mi][kk] = (ra << 7) + (kb ^ ((ra & 7) << 4));
        }
    #pragma unroll
    for (int ni = 0; ni < NI; ++ni)
        #pragma unroll
        for (int kk = 0; kk < 2; ++kk) {
            int kb = (kk << 6) + (kg << 4);
            int rb = wn + (ni << 4) + fr;
            offB[ni][kk] = ABYT + (rb << 7) + (kb ^ ((rb & 7) << 4));
        }

    auto stage = [&](int sb, int k0) {
        char* base = lds + sb * STG;
        #pragma unroll
        for (int c = 0; c < ACH / 256; ++c) {
            int idx = c * 256 + tid;
            int row = idx >> 3, kb = (idx & 7) << 4;
            gl2lds16((const char*)A + (((size_t)(bm + row) * K + k0) << 1) + (kb ^ ((row & 7) << 4)),
                     base + idx * 16);
        }
        #pragma unroll
        for (int c = 0; c < 2; ++c) {
            int idx = c * 256 + tid;
            int row = idx >> 3, kb = (idx & 7) << 4;
            gl2lds16((const char*)Bt + (((size_t)(bn + row) * K + k0) << 1) + (kb ^ ((row & 7) << 4)),
                     base + ABYT + idx * 16);
        }
    };

    f32x4 acc[2][2] = {};
    const int NK = K >> 6;
    stage(0, 0);
    for (int ks = 0; ks < NK; ++ks) {
        const int cur = ks & 1;
        if (ks + 1 < NK) { stage(cur ^ 1, (ks + 1) << 6); vmw<LPT>(); }
        else vmw<0>();
        bar();                               // stage ks data visible in LDS
        const char* bp = lds + cur * STG;
        bf16x8 af[2][2], bf_[2][2];
        #pragma unroll
        for (int mi = 0; mi < 2; ++mi)
            #pragma unroll
            for (int kk = 0; kk < 2; ++kk)
                af[mi][kk] = *(const bf16x8*)(bp + offA[mi][kk]);
        #pragma unroll
        for (int ni = 0; ni < NI; ++ni)
            #pragma unroll
            for (int kk = 0; kk < 2; ++kk)
                bf_[ni][kk] = *(const bf16x8*)(bp + offB[ni][kk]);
        #pragma unroll
        for (int kk = 0; kk < 2; ++kk)
            #pragma unroll
            for (int mi = 0; mi < 2; ++mi)
                #pragma unroll
                for (int ni = 0; ni < NI; ++ni)
                    acc[mi][ni] = __builtin_amdgcn_mfma_f32_16x16x32_bf16(
                        af[mi][kk], bf_[ni][kk], acc[mi][ni], 0, 0, 0);
        asm volatile("s_waitcnt lgkmcnt(0)" ::: "memory");
        bar();                               // buf[cur] reusable next+1 iter
    }

    const int rb4 = kg << 2;
    float b_[NI], w_[NI];
    #pragma unroll
    for (int ni = 0; ni < NI; ++ni) {
        int col = bn + wn + (ni << 4) + fr;
        b_[ni] = bias[col];
        if (EPI == 6) w_[ni] = aux[col];
    }
    #pragma unroll
    for (int mi = 0; mi < 2; ++mi)
        #pragma unroll
        for (int r = 0; r < 4; ++r) {
            const int row = bm + wm + (mi << 4) + rb4 + r;
            if (row >= M) continue;          // uniform over fr-group
            float mean = 0.f, rinv = 0.f;
            if (EPI == 6) {
                float s0 = stats[row * 2 + 0], s1 = stats[row * 2 + 1];
                mean = s0 * (1.f / 512.f);
                rinv = rsqrtf(s1 * (1.f / 512.f) - mean * mean + EPSLN);
            }
            float vs = 0.f, vq = 0.f;
            #pragma unroll
            for (int ni = 0; ni < NI; ++ni) {
                const int col = bn + wn + (ni << 4) + fr;
                float v = acc[mi][ni][r];
                if (EPI == 6) v = rinv * v - mean * rinv * w_[ni] + b_[ni];
                else v += b_[ni];
                if (EPI == 4 || EPI == 5) v += res[(size_t)row * N + col];
                if (EPI == 6) {
                    float g = 0.5f * v * (1.f + tanhf(0.7978845608028654f * (v + 0.044715f * v * v * v)));
                    Cb[(size_t)row * N + col] = __float2bfloat16(g);
                } else if (EPI == 3) {
                    Cb[(size_t)row * N + col] = __float2bfloat16(v);
                } else if (EPI == 4) {
                    Cf[(size_t)row * N + col] = v;
                    Cb[(size_t)row * N + col] = __float2bfloat16(v);
                } else if (EPI == 5) {
                    Cf[(size_t)row * N + col] = v;
                    Cb[(size_t)row * N + col] = __float2bfloat16(v);
                    vs += v; vq += v * v;
                } else {
                    Cf[(size_t)row * N + col] = v;
                }
            }
            if (EPI == 5) {
                #pragma unroll
                for (int m2 = 1; m2 < 16; m2 <<= 1) {
                    vs += __shfl_xor(vs, m2);
                    vq += __shfl_xor(vq, m2);
                }
                if (fr == 0) {
                    atomicAdd(&stats[row * 2 + 0], vs);
                    atomicAdd(&stats[row * 2 + 1], vq);
                }
            }
        }
}

// ---------------- halting GEMM: z[row][0:2] += tanh(chi@Wh1+bh1) @ Wh2 ----------------
// Plain bf16. N=K=512 fixed. BM=32, double-buffered.
__global__ __launch_bounds__(256)
void halt_gemm(const __hip_bfloat16* __restrict__ Ahp, const __hip_bfloat16* __restrict__ Bhp,
               const float* __restrict__ bh1, const float* __restrict__ Wh2,
               float* __restrict__ z, int M)
{
    constexpr int STG = 12288;   // Ah 4K @0, Bh 8K @4096
    __shared__ char lds[2 * STG];
    const int tid = threadIdx.x;
    const int bm = blockIdx.y << 5, bn = blockIdx.x << 6;
    const int lane = tid & 63, wv = tid >> 6;
    const int wn = wv << 4;
    const int fr = lane & 15, kg = lane >> 4;

    int offA[2][2], offB[2];
    #pragma unroll
    for (int mi = 0; mi < 2; ++mi)
        #pragma unroll
        for (int kk = 0; kk < 2; ++kk) {
            int kb = (kk << 6) + (kg << 4);
            int ra = (mi << 4) + fr;
            offA[mi][kk] = (ra << 7) + (kb ^ ((ra & 7) << 4));
        }
    #pragma unroll
    for (int kk = 0; kk < 2; ++kk) {
        int kb = (kk << 6) + (kg << 4);
        int rb = wn + fr;
        offB[kk] = 4096 + (rb << 7) + (kb ^ ((rb & 7) << 4));
    }

    auto stage = [&](int sb, int k0) {
        char* base = lds + sb * STG;
        {
            int row = tid >> 3, kb = (tid & 7) << 4;
            int swz = kb ^ ((row & 7) << 4);
            size_t aoff = (((size_t)(bm + row) * 512 + k0) << 1) + swz;
            gl2lds16((const char*)Ahp + aoff, base + tid * 16);
        }
        #pragma unroll
        for (int c = 0; c < 2; ++c) {
            int idx = c * 256 + tid;
            int row = idx >> 3, kb = (idx & 7) << 4;
            int swz = kb ^ ((row & 7) << 4);
            size_t boff = (((size_t)(bn + row) * 512 + k0) << 1) + swz;
            gl2lds16((const char*)Bhp + boff, base + 4096 + idx * 16);
        }
    };

    f32x4 acc[2] = {};
    stage(0, 0);
    for (int ks = 0; ks < 8; ++ks) {
        const int cur = ks & 1;
        if (ks < 7) { stage(cur ^ 1, (ks + 1) << 6); vmw<3>(); }
        else vmw<0>();
        bar();
        const char* bp = lds + cur * STG;
        bf16x8 ah[2][2], bh_[2];
        #pragma unroll
        for (int mi = 0; mi < 2; ++mi)
            #pragma unroll
            for (int kk = 0; kk < 2; ++kk)
                ah[mi][kk] = *(const bf16x8*)(bp + offA[mi][kk]);
        #pragma unroll
        for (int kk = 0; kk < 2; ++kk)
            bh_[kk] = *(const bf16x8*)(bp + offB[kk]);
        #pragma unroll
        for (int kk = 0; kk < 2; ++kk)
            #pragma unroll
            for (int mi = 0; mi < 2; ++mi)
                acc[mi] = __builtin_amdgcn_mfma_f32_16x16x32_bf16(ah[mi][kk], bh_[kk], acc[mi], 0, 0, 0);
        asm volatile("s_waitcnt lgkmcnt(0)" ::: "memory");
        bar();
    }

    const int col = bn + wn + fr;
    const float b_ = bh1[col];
    const float w0_ = Wh2[col * 2 + 0];
    const float w1_ = Wh2[col * 2 + 1];
    #pragma unroll
    for (int mi = 0; mi < 2; ++mi)
        #pragma unroll
        for (int r = 0; r < 4; ++r) {
            float v = tanhf(acc[mi][r] + b_);
            float p0 = v * w0_;
            float p1 = v * w1_;
            #pragma unroll
            for (int m2 = 1; m2 < 16; m2 <<= 1) {
                p0 += __shfl_xor(p0, m2);
                p1 += __shfl_xor(p1, m2);
            }
            if (fr == 0) {
                int row = bm + (mi << 4) + (kg << 2) + r;
                if (row < M) {
                    atomicAdd(&z[row * 2 + 0], p0);
                    atomicAdd(&z[row * 2 + 1], p1);
                }
            }
        }
}

// ---------------- MFMA attention ----------------
// grid (5 q-chunks, 8 heads, 16 batch), 256 threads. All inputs read from bf16 qkvb.
// Distributed in-register ONE-BARRIER softmax: each wave publishes (m_w, sum_w=
// sum exp(s-m_w)); after one barrier, gm/tot combined per row. P aliases dead KT.
#define KT_BASE 0          // [144][128B] XOR-swizzled K (B-layout)   18432
#define P_BASE  0          // [32][336B] bf16 softmax — ALIASES KT    10752
#define VT_BASE 18432      // [64][384B] XOR-swizzled V^T             24576
#define QC_BASE 43008      // [32][72] bf16 q+cb (stride 144B)         4608
#define R_BASE  47616      // [32][8] f32 rel logits                   1024
#define WM_BASE 48640      // [4][32] f32 per-wave row max              512
#define WS_BASE 49152      // [4][32] f32 per-wave row sum              512
__global__ __launch_bounds__(256)
void attn_mfma(const __hip_bfloat16* __restrict__ qkvb,
               const float* __restrict__ rk7, const float* __restrict__ cbias,
               const float* __restrict__ rbias, __hip_bfloat16* __restrict__ aout)
{
    __shared__ char lds[49664];
    const int tid = threadIdx.x;
    const int chunk = blockIdx.x, hh = blockIdx.y, b = blockIdx.z;
    const int q0 = chunk << 5;
    const int lane = tid & 63, wv = tid >> 6;
    const int fr = lane & 15, kg = lane >> 4;
    const size_t qrow0 = (size_t)b * Sc;
    const short* qs = (const short*)qkvb;

    // phase 0: zero VT (full 24576B) + Kt pad rows 129..143
    {
        f32x4 zz = {};
        #pragma unroll
        for (int i = 0; i < 6; ++i)
            *(f32x4*)(lds + VT_BASE + (i * 256 + tid) * 16) = zz;
        if (tid < 120)
            *(f32x4*)(lds + KT_BASE + 129 * 128 + tid * 16) = zz;
    }
    __syncthreads();

    // stage Kt (rows 0..128) via global_load_lds, XOR pre-swizzled source
    #pragma unroll
    for (int i = 0; i < 5; ++i) {
        int idx = i * 256 + tid;
        if (idx < 1152) {
            int row = idx >> 3, ch = idx & 7;
            if (row <= 128) {
                const char* src = (const char*)qkvb +
                    (((qrow0 + row) * 1536 + 512 + (size_t)hh * 64) << 1) + ((ch ^ (row & 7)) << 4);
                gl2lds16(src, lds + KT_BASE + idx * 16);
            }
        }
    }
    // stage V^T: swizzled scatter writes (conflict-free by key=(g^j))
    #pragma unroll
    for (int i = 0; i < 5; ++i) {
        int idx = i * 256 + tid;
        if (idx < 1032) {                    // 129 T-slots x 8 d-groups
            int T = idx >> 3, g = idx & 7;
            bf16x8 v = *(const bf16x8*)(qs + (qrow0 + T) * 1536 + 1024 + hh * 64 + g * 8);
            #pragma unroll
            for (int j = 0; j < 8; ++j) {
                int row = g * 8 + j;
                int key = (g ^ j) & 7;
                *(short*)(lds + VT_BASE + row * 384 + ((T * 2) ^ (key << 4))) = v[j];
            }
        }
    }
    // stage Qc = bf16(q + content_bias): 256 threads = 32 rows x 8 groups
    {
        int row = tid >> 3, g = tid & 7;
        bf16x8 q8 = *(const bf16x8*)(qs + (qrow0 + q0 + row) * 1536 + hh * 64 + g * 8);
        const float* cb = cbias + hh * 64 + g * 8;
        bf16x8 o8;
        #pragma unroll
        for (int j = 0; j < 8; ++j)
            o8[j] = f2bf(bf2f(q8[j]) + cb[j]);
        *(bf16x8*)(lds + QC_BASE + row * 144 + g * 16) = o8;
    }
    // R[row][c] = (q + rbias) . rk7[c], bf16 q loads vectorized
    if (tid < 224) {
        int row = tid / 7, c = tid % 7;
        const short* qp = qs + (qrow0 + q0 + row) * 1536 + hh * 64;
        const float* rp  = rk7 + c * 512 + hh * 64;
        const float* rbp = rbias + hh * 64;
        float a = 0.f;
        #pragma unroll
        for (int g = 0; g < 8; ++g) {
            bf16x8 q8 = *(const bf16x8*)(qp + g * 8);
            #pragma unroll
            for (int j = 0; j < 8; ++j)
                a += (bf2f(q8[j]) + rbp[g * 8 + j]) * rp[g * 8 + j];
        }
        *(float*)(lds + R_BASE + (row * 8 + c) * 4) = a;
    }
    __syncthreads();

    // QK^T: 9 N-tiles over 4 waves
    f32x4 acc[2][3] = {};
    __builtin_amdgcn_s_setprio(1);
    #pragma unroll
    for (int ni = 0; ni < 3; ++ni) {
        int nt = wv + ni * 4;
        if (nt > 8) continue;
        #pragma unroll
        for (int mt = 0; mt < 2; ++mt)
            #pragma unroll
            for (int ks = 0; ks < 2; ++ks) {
                bf16x8 a = *(const bf16x8*)(lds + QC_BASE + (mt * 16 + fr) * 144 + ks * 64 + kg * 16);
                int rowb = nt * 16 + fr;
                bf16x8 bb = *(const bf16x8*)(lds + KT_BASE + rowb * 128 +
                                             ((ks * 64 + kg * 16) ^ ((rowb & 7) << 4)));
                acc[mt][ni] = __builtin_amdgcn_mfma_f32_16x16x32_bf16(a, bb, acc[mt][ni], 0, 0, 0);
            }
    }
    __builtin_amdgcn_s_setprio(0);

    // s = (cl + rl)*scale, masked — in registers (overwrite acc)
    #pragma unroll
    for (int ni = 0; ni < 3; ++ni) {
        int nt = wv + ni * 4;
        int col = nt * 16 + fr;
        #pragma unroll
        for (int mt = 0; mt < 2; ++mt)
            #pragma unroll
            for (int r = 0; r < 4; ++r) {
                int row = mt * 16 + kg * 4 + r;
                float sv = -1e30f;
                if (nt <= 8 && col <= 128) {
                    int delta = q0 + row - col;
                    int c = delta >= 3 ? 3 : (delta <= -3 ? 4 : (delta < 0 ? delta + 7 : delta));
                    float rl = *(const float*)(lds + R_BASE + (row * 8 + c) * 4);
                    sv = (acc[mt][ni][r] + rl) * 0.125f;
                }
                acc[mt][ni][r] = sv;
            }
    }

    // per-wave max + per-wave exp-sum (relative to own max), ONE barrier
    float m_[2][4], su[2][4];
    #pragma unroll
    for (int mt = 0; mt < 2; ++mt)
        #pragma unroll
        for (int r = 0; r < 4; ++r) {
            float m = fmaxf(fmaxf(acc[mt][0][r], acc[mt][1][r]), acc[mt][2][r]);
            #pragma unroll
            for (int b2 = 1; b2 < 16; b2 <<= 1) m = fmaxf(m, __shfl_xor(m, b2));
            m_[mt][r] = m;
            su[mt][r] = 0.f;
        }
    #pragma unroll
    for (int ni = 0; ni < 3; ++ni)
        #pragma unroll
        for (int mt = 0; mt < 2; ++mt)
            #pragma unroll
            for (int r = 0; r < 4; ++r) {
                float s = acc[mt][ni][r];
                float e = (s > -1e29f) ? expf(s - m_[mt][r]) : 0.f;
                acc[mt][ni][r] = e;
                su[mt][r] += e;
            }
    #pragma unroll
    for (int mt = 0; mt < 2; ++mt)
        #pragma unroll
        for (int r = 0; r < 4; ++r) {
            float s = su[mt][r];
            #pragma unroll
            for (int b2 = 1; b2 < 16; b2 <<= 1) s += __shfl_xor(s, b2);
            su[mt][r] = s;
        }
    if (fr == 0) {
        float* wm = (float*)(lds + WM_BASE) + (wv << 5);
        float* ws = (float*)(lds + WS_BASE) + (wv << 5);
        #pragma unroll
        for (int mt = 0; mt < 2; ++mt)
            #pragma unroll
            for (int r = 0; r < 4; ++r) {
                wm[mt * 16 + (kg << 2) + r] = m_[mt][r];
                ws[mt * 16 + (kg << 2) + r] = su[mt][r];
            }
    }
    __syncthreads();                        // bar1: softmax partials ready; KT dead

    // zero P cols 144..159 (32 rows x 32B), safe after bar1
    if (tid < 128) {
        int row = tid >> 2;
        *(double*)(lds + P_BASE + row * 336 + 288 + (tid & 3) * 8) = 0.0;
    }

    // combine: gm = max over waves; tot = sum ws_w * exp(wm_w - gm);
    // this wave's scale = exp(m_self - gm)/tot
    const float* wmv = (const float*)(lds + WM_BASE);
    const float* wsv = (const float*)(lds + WS_BASE);
    float fac[2][4];
    #pragma unroll
    for (int mt = 0; mt < 2; ++mt)
        #pragma unroll
        for (int r = 0; r < 4; ++r) {
            int row = mt * 16 + (kg << 2) + r;
            float m0 = wmv[row],      m1 = wmv[32 + row];
            float m2 = wmv[64 + row], m3 = wmv[96 + row];
            float gm = fmaxf(fmaxf(m0, m1), fmaxf(m2, m3));
            float tot = wsv[row] * expf(m0 - gm) + wsv[32 + row] * expf(m1 - gm)
                      + wsv[64 + row] * expf(m2 - gm) + wsv[96 + row] * expf(m3 - gm);
            fac[mt][r] = expf(m_[mt][r] - gm) / tot;
        }
    // P write (bf16) into aliased KT region
    #pragma unroll
    for (int ni = 0; ni < 3; ++ni) {
        int nt = wv + ni * 4;
        if (nt > 8) continue;
        int col = nt * 16 + fr;
        #pragma unroll
        for (int mt = 0; mt < 2; ++mt)
            #pragma unroll
            for (int r = 0; r < 4; ++r) {
                int row = mt * 16 + (kg << 2) + r;
                *(short*)(lds + P_BASE + row * 336 + col * 2) =
                    f2bf(acc[mt][ni][r] * fac[mt][r]);
            }
    }
    __syncthreads();                        // bar2: P ready

    // PV: wave owns 16 output dims; V^T read with matching XOR swizzle
    f32x4 acc2[2] = {};
    const int rowv = wv * 16 + fr;
    const int keyv = ((rowv >> 3) ^ rowv) & 7;
    __builtin_amdgcn_s_setprio(1);
    #pragma unroll
    for (int mt = 0; mt < 2; ++mt)
        #pragma unroll
        for (int ks = 0; ks < 5; ++ks) {
            bf16x8 a  = *(const bf16x8*)(lds + P_BASE + (mt * 16 + fr) * 336 + ks * 64 + kg * 16);
            bf16x8 bb = *(const bf16x8*)(lds + VT_BASE + rowv * 384 +
                                         ((ks * 64 + kg * 16) ^ (keyv << 4)));
            acc2[mt] = __builtin_amdgcn_mfma_f32_16x16x32_bf16(a, bb, acc2[mt], 0, 0, 0);
        }
    __builtin_amdgcn_s_setprio(0);
    #pragma unroll
    for (int mt = 0; mt < 2; ++mt)
        #pragma unroll
        for (int r = 0; r < 4; ++r) {
            int t = q0 + mt * 16 + kg * 4 + r;
            if (t <= 128)
                aout[(qrow0 + t) * 512 + hh * 64 + wv * 16 + fr] = __float2bfloat16(acc2[mt][r]);
        }
}

// ---------------- ACT bookkeeping + LN(curr) + blend + h_out ----------------
// 4 rows per block, one 64-lane wave per row; no LDS, no syncthreads.
__global__ __launch_bounds__(256)
void haltblend(const float* __restrict__ curr, const float* __restrict__ s,
               const float* __restrict__ o, float* __restrict__ zbuf,
               float* __restrict__ lanh, float* __restrict__ lah,
               float* __restrict__ h, __hip_bfloat16* __restrict__ hb,
               float* __restrict__ hout, float* __restrict__ stats)
{
    const int row = (blockIdx.x << 2) + (threadIdx.x >> 6);
    const int lane = threadIdx.x & 63;

    float z0 = zbuf[row * 2 + 0] + 2.f;
    float z1 = zbuf[row * 2 + 1] - 2.f;
    float mxz = fmaxf(z0, z1);
    float lse = mxz + logf(expf(z0 - mxz) + expf(z1 - mxz));
    float lg0 = z0 - lse, lg1 = z1 - lse;
    float ln_ = lanh[row], la_ = lah[row];
    float lhalt = ln_ + lg1;
    float hl = expf(la_);            // PRE-update lah
    float ph = expf(lhalt);

    const size_t rbase = (size_t)row * 512;
    const int c0 = lane << 3;
    f32x4 x0 = *(const f32x4*)(curr + rbase + c0);
    f32x4 x1 = *(const f32x4*)(curr + rbase + c0 + 4);
    float sum = (x0[0] + x0[1]) + (x0[2] + x0[3]) + (x1[0] + x1[1]) + (x1[2] + x1[3]);
    float sq  = (x0[0] * x0[0] + x0[1] * x0[1]) + (x0[2] * x0[2] + x0[3] * x0[3])
              + (x1[0] * x1[0] + x1[1] * x1[1]) + (x1[2] * x1[2] + x1[3] * x1[3]);
    #pragma unroll
    for (int m2 = 1; m2 < 64; m2 <<= 1) { sum += __shfl_xor(sum, m2); sq += __shfl_xor(sq, m2); }
    float mean = sum * (1.f / 512.f);
    float inv = rsqrtf(sq * (1.f / 512.f) - mean * mean + EPSLN);

    if (lane == 0) {
        lanh[row] = ln_ + lg0;
        float m3 = fmaxf(la_, lhalt);
        lah[row] = m3 + logf(expf(la_ - m3) + expf(lhalt - m3));
        zbuf[row * 2 + 0] = 0.f;
        zbuf[row * 2 + 1] = 0.f;
        stats[row * 2 + 0] = 0.f;    // reset LN stats for next iteration's Wo epilogue
        stats[row * 2 + 1] = 0.f;
    }

    f32x4 sv0 = *(const f32x4*)(s + c0), sv1 = *(const f32x4*)(s + c0 + 4);
    f32x4 ov0 = *(const f32x4*)(o + c0), ov1 = *(const f32x4*)(o + c0 + 4);
    f32x4 hv0 = *(f32x4*)(h + rbase + c0), hv1 = *(f32x4*)(h + rbase + c0 + 4);
    f32x4 ho0 = *(f32x4*)(hout + rbase + c0), ho1 = *(f32x4*)(hout + rbase + c0 + 4);
    u16x4 hb0, hb1;
    #pragma unroll
    for (int e = 0; e < 4; ++e) {
        float cl = (x0[e] - mean) * inv * sv0[e] + ov0[e];
        float hn = hl * hv0[e] + (1.f - hl) * cl;
        hv0[e] = hn;
        __hip_bfloat16 bb = __float2bfloat16(hn);
        hb0[e] = *reinterpret_cast<unsigned short*>(&bb);
        ho0[e] += ph * cl;
    }
    #pragma unroll
    for (int e = 0; e < 4; ++e) {
        float cl = (x1[e] - mean) * inv * sv1[e] + ov1[e];
        float hn = hl * hv1[e] + (1.f - hl) * cl;
        hv1[e] = hn;
        __hip_bfloat16 bb = __float2bfloat16(hn);
        hb1[e] = *reinterpret_cast<unsigned short*>(&bb);
        ho1[e] += ph * cl;
    }
    *(f32x4*)(h + rbase + c0) = hv0;
    *(f32x4*)(h + rbase + c0 + 4) = hv1;
    *(u16x4*)(reinterpret_cast<unsigned short*>(hb) + rbase + c0) = hb0;
    *(u16x4*)(reinterpret_cast<unsigned short*>(hb) + rbase + c0 + 4) = hb1;
    *(f32x4*)(hout + rbase + c0) = ho0;
    *(f32x4*)(hout + rbase + c0 + 4) = ho1;
}

// ---------------- setup kernels ----------------
__global__ __launch_bounds__(256)
void emb_kernel(const float* __restrict__ x, const float* __restrict__ We,
                const float* __restrict__ eos, const float* __restrict__ s,
                const float* __restrict__ o, float* __restrict__ h,
                __hip_bfloat16* __restrict__ hb)
{
    int row = blockIdx.x, tid = threadIdx.x;
    int b = row / Sc, t = row % Sc;
    __shared__ float xs[64];
    if (t != 128 && tid < 64) xs[tid] = x[((size_t)b * 128 + t) * 64 + tid];
    __syncthreads();
    float v0, v1;
    if (t == 128) {
        v0 = eos[tid]; v1 = eos[tid + 256];
    } else {
        v0 = 0.f; v1 = 0.f;
        #pragma unroll 8
        for (int k = 0; k < 64; ++k) {
            float xv = xs[k];
            v0 = fmaf(xv, We[k * 512 + tid], v0);
            v1 = fmaf(xv, We[k * 512 + tid + 256], v1);
        }
    }
    float sum = v0 + v1, sq = v0 * v0 + v1 * v1;
    #pragma unroll
    for (int m2 = 1; m2 < 64; m2 <<= 1) { sum += __shfl_xor(sum, m2); sq += __shfl_xor(sq, m2); }
    __shared__ float ssum[4], ssq[4];
    if ((tid & 63) == 0) { ssum[tid >> 6] = sum; ssq[tid >> 6] = sq; }
    __syncthreads();
    float tot = ssum[0] + ssum[1] + ssum[2] + ssum[3];
    float totq = ssq[0] + ssq[1] + ssq[2] + ssq[3];
    float mean = tot * (1.f / 512.f);
    float inv = rsqrtf(totq * (1.f / 512.f) - mean * mean + EPSLN);
    float h0 = (v0 - mean) * inv * s[tid] + o[tid];
    float h1 = (v1 - mean) * inv * s[tid + 256] + o[tid + 256];
    h[(size_t)row * 512 + tid] = h0;
    h[(size_t)row * 512 + tid + 256] = h1;
    hb[(size_t)row * 512 + tid] = __float2bfloat16(h0);
    hb[(size_t)row * 512 + tid + 256] = __float2bfloat16(h1);
}

__global__ __launch_bounds__(256)
void rk7_kernel(const float* __restrict__ pos, const float* __restrict__ Wk,
                const float* __restrict__ bk, float* __restrict__ rk7)
{
    int c = blockIdx.x, tid = threadIdx.x;
    __shared__ float ps[512];
    ps[tid] = pos[c * 512 + tid];
    ps[tid + 256] = pos[c * 512 + tid + 256];
    __syncthreads();
    float a0 = bk[tid], a1 = bk[tid + 256];
    for (int k = 0; k < 512; ++k) {
        float pv = ps[k];
        a0 = fmaf(pv, Wk[(size_t)k * 512 + tid], a0);
        a1 = fmaf(pv, Wk[(size_t)k * 512 + tid + 256], a1);
    }
    rk7[c * 512 + tid] = a0;
    rk7[c * 512 + tid + 256] = a1;
}

__global__ __launch_bounds__(256)
void pack_qkvT(const float* __restrict__ Wq, const float* __restrict__ Wk,
               const float* __restrict__ Wv, __hip_bfloat16* __restrict__ Wt)
{
    int idx = blockIdx.x * 256 + threadIdx.x;
    if (idx >= 1536 * 512) return;
    int n = idx >> 9, k = idx & 511;
    const float* src = (n < 512) ? Wq : (n < 1024) ? Wk : Wv;
    int nc = n & 511;
    Wt[idx] = __float2bfloat16(src[(size_t)k * 512 + nc]);
}

__global__ __launch_bounds__(256)
void transposeT(const float* __restrict__ W, __hip_bfloat16* __restrict__ Wt, int K, int N)
{
    int idx = blockIdx.x * 256 + threadIdx.x;
    if (idx >= K * N) return;
    int n = idx / K, k = idx - n * K;
    Wt[idx] = __float2bfloat16(W[(size_t)k * N + n]);
}

// Wt[n][k] = bf16(W[k][n] * s[k])   (fold LN scale into W1)
__global__ __launch_bounds__(256)
void transposeT_scale(const float* __restrict__ W, const float* __restrict__ s,
                      __hip_bfloat16* __restrict__ Wt, int K, int N)
{
    int idx = blockIdx.x * 256 + threadIdx.x;
    if (idx >= K * N) return;
    int n = idx / K, k = idx - n * K;
    Wt[idx] = __float2bfloat16(W[(size_t)k * N + n] * s[k]);
}

// w1sum[n] = sum_k s[k]*W[k][n];  b1f[n] = b[n] + sum_k o[k]*W[k][n]
__global__ __launch_bounds__(256)
void fold_w1(const float* __restrict__ W, const float* __restrict__ s,
             const float* __restrict__ o, const float* __restrict__ b,
             float* __restrict__ w1sum, float* __restrict__ b1f, int K, int N)
{
    int n = blockIdx.x * 256 + threadIdx.x;
    if (n >= N) return;
    float ws = 0.f, bo_ = b[n];
    for (int k = 0; k < K; ++k) {
        float w = W[(size_t)k * N + n];
        ws = fmaf(s[k], w, ws);
        bo_ = fmaf(o[k], w, bo_);
    }
    w1sum[n] = ws;
    b1f[n] = bo_;
}

__global__ __launch_bounds__(256)
void pack_bias(const float* __restrict__ bq, const float* __restrict__ bk,
               const float* __restrict__ bv, float* __restrict__ bqkv)
{
    int idx = blockIdx.x * 256 + threadIdx.x;
    if (idx < 1536)
        bqkv[idx] = (idx < 512) ? bq[idx] : (idx < 1024) ? bk[idx - 512] : bv[idx - 1024];
}

__global__ __launch_bounds__(256)
void init_kernel(float* __restrict__ lanh, float* __restrict__ lah,
                 float* __restrict__ zbuf, float* __restrict__ stats)
{
    int idx = blockIdx.x * 256 + threadIdx.x;
    if (idx < Mc) {
        lanh[idx] = 0.f; lah[idx] = -64.f;
        zbuf[idx * 2 + 0] = 0.f; zbuf[idx * 2 + 1] = 0.f;
    }
    if (idx < MP) {
        stats[idx * 2 + 0] = 0.f; stats[idx * 2 + 1] = 0.f;
    }
}

// ---------------- host launcher ----------------
extern "C" void kernel_launch(void* const* d_in, const int* in_sizes, int n_in,
                              void* d_out, int out_size, void* d_ws, size_t ws_size,
                              hipStream_t stream)
{
    const float* x     = (const float*)d_in[0];
    const float* We    = (const float*)d_in[1];
    const float* eos   = (const float*)d_in[2];
    const float* Wq    = (const float*)d_in[3];
    const float* bq    = (const float*)d_in[4];
    const float* Wk    = (const float*)d_in[5];
    const float* bk    = (const float*)d_in[6];
    const float* Wv    = (const float*)d_in[7];
    const float* bv    = (const float*)d_in[8];
    const float* Wo    = (const float*)d_in[9];
    const float* bo    = (const float*)d_in[10];
    const float* cbias = (const float*)d_in[11];
    const float* rbias = (const float*)d_in[12];
    const float* pos   = (const float*)d_in[13];
    const float* ln2s  = (const float*)d_in[14];
    const float* ln2o  = (const float*)d_in[15];
    const float* lnos  = (const float*)d_in[16];
    const float* lnoo  = (const float*)d_in[17];
    const float* W1    = (const float*)d_in[18];
    const float* b1    = (const float*)d_in[19];
    const float* W2    = (const float*)d_in[20];
    const float* b2    = (const float*)d_in[21];
    const float* Wh1   = (const float*)d_in[22];
    const float* bh1   = (const float*)d_in[23];
    const float* Wh2   = (const float*)d_in[24];
    (void)in_sizes; (void)n_in; (void)ws_size;

    char* wp = (char*)d_ws;
    auto alloc = [&](size_t bytes) { char* p = wp; wp += (bytes + 255) & ~(size_t)255; return p; };
    float*          h     = (float*)alloc((size_t)MP * 512 * 4);
    __hip_bfloat16* hb    = (__hip_bfloat16*)alloc((size_t)MP * 512 * 2);
    __hip_bfloat16* qkvb  = (__hip_bfloat16*)alloc((size_t)MP * 1536 * 2);
    __hip_bfloat16* abufb = (__hip_bfloat16*)alloc((size_t)MP * 512 * 2);
    float*          hmid  = (float*)alloc((size_t)MP * 512 * 4);
    __hip_bfloat16* hmidb = (__hip_bfloat16*)alloc((size_t)MP * 512 * 2);
    __hip_bfloat16* g1b   = (__hip_bfloat16*)alloc((size_t)MP * 1024 * 2);
    float*          curr  = (float*)alloc((size_t)MP * 512 * 4);
    __hip_bfloat16* chi   = (__hip_bfloat16*)alloc((size_t)MP * 512 * 2);
    __hip_bfloat16* WqkvT = (__hip_bfloat16*)alloc((size_t)1536 * 512 * 2);
    __hip_bfloat16* WoT   = (__hip_bfloat16*)alloc((size_t)512 * 512 * 2);
    __hip_bfloat16* W1T   = (__hip_bfloat16*)alloc((size_t)1024 * 512 * 2);
    __hip_bfloat16* W2T   = (__hip_bfloat16*)alloc((size_t)512 * 1024 * 2);
    __hip_bfloat16* Wh1Th = (__hip_bfloat16*)alloc((size_t)512 * 512 * 2);
    float*          bqkv  = (float*)alloc(1536 * 4);
    float*          w1sum = (float*)alloc(1024 * 4);
    float*          b1f   = (float*)alloc(1024 * 4);
    float*          rk7   = (float*)alloc(7 * 512 * 4);
    float*          lanh  = (float*)alloc(Mc * 4);
    float*          lah   = (float*)alloc(Mc * 4);
    float*          zbuf  = (float*)alloc((size_t)Mc * 2 * 4);
    float*          stats = (float*)alloc((size_t)MP * 2 * 4);
    float* hout = (float*)d_out;

    hipMemsetAsync(d_out, 0, (size_t)out_size * sizeof(float), stream);
    init_kernel<<<(MP + 255) / 256, 256, 0, stream>>>(lanh, lah, zbuf, stats);
    pack_qkvT<<<(1536 * 512 + 255) / 256, 256, 0, stream>>>(Wq, Wk, Wv, WqkvT);
    transposeT<<<(512 * 512 + 255) / 256, 256, 0, stream>>>(Wo, WoT, 512, 512);
    transposeT_scale<<<(512 * 1024 + 255) / 256, 256, 0, stream>>>(W1, ln2s, W1T, 512, 1024);
    fold_w1<<<4, 256, 0, stream>>>(W1, ln2s, ln2o, b1, w1sum, b1f, 512, 1024);
    transposeT<<<(1024 * 512 + 255) / 256, 256, 0, stream>>>(W2, W2T, 1024, 512);
    transposeT<<<(512 * 512 + 255) / 256, 256, 0, stream>>>(Wh1, Wh1Th, 512, 512);
    pack_bias<<<(1536 + 255) / 256, 256, 0, stream>>>(bq, bk, bv, bqkv);
    rk7_kernel<<<7, 256, 0, stream>>>(pos, Wk, bk, rk7);
    emb_kernel<<<Mc, 256, 0, stream>>>(x, We, eos, lnos, lnoo, h, hb);

    for (int it = 0; it < ITERS; ++it) {
        mgemm<3, 64><<<dim3(24, 33), 256, 0, stream>>>(
            hb, WqkvT, bqkv, nullptr, nullptr, qkvb, nullptr, nullptr, Mc, 1536, 512);
        attn_mfma<<<dim3(5, 8, 16), 256, 0, stream>>>(qkvb, rk7, cbias, rbias, abufb);
        mgemm<5, 32><<<dim3(8, 66), 256, 0, stream>>>(
            abufb, WoT, bo, h, hmid, hmidb, stats, nullptr, Mc, 512, 512);
        mgemm<6, 64><<<dim3(16, 33), 256, 0, stream>>>(
            hmidb, W1T, b1f, nullptr, nullptr, g1b, stats, w1sum, Mc, 1024, 512);
        mgemm<4, 32><<<dim3(8, 66), 256, 0, stream>>>(
            g1b, W2T, b2, hmid, curr, chi, nullptr, nullptr, Mc, 512, 1024);
        halt_gemm<<<dim3(8, 66), 256, 0, stream>>>(chi, Wh1Th, bh1, Wh2, zbuf, Mc);
        haltblend<<<Mc / 4, 256, 0, stream>>>(curr, lnos, lnoo, zbuf, lanh, lah, h, hb, hout, stats);
    }
}

// Round 13
// 9651.975 us; speedup vs baseline: 1.1519x; 1.1436x over previous
//
#include <hip/hip_runtime.h>
#include <hip/hip_bf16.h>
#include <cstdint>
#include <cmath>

#define EPSLN 1e-5f

typedef __attribute__((ext_vector_type(8))) short bf16x8;
typedef __attribute__((ext_vector_type(4))) float f32x4;
typedef __attribute__((ext_vector_type(4))) unsigned short u16x4;

constexpr int Bc = 16;
constexpr int Sc = 129;          // T+1
constexpr int Mc = Bc * Sc;      // 2064 rows (real)
constexpr int MP = 2112;         // padded rows = 33*64 = 66*32
constexpr int ITERS = 127;       // T-1

__device__ __forceinline__ void gl2lds16(const void* g, void* l) {
    __builtin_amdgcn_global_load_lds(
        (const __attribute__((address_space(1))) unsigned int*)g,
        (__attribute__((address_space(3))) unsigned int*)l, 16, 0, 0);
}

template<int N> __device__ __forceinline__ void vmw() {
    if constexpr (N == 0) asm volatile("s_waitcnt vmcnt(0)" ::: "memory");
    else if constexpr (N == 3) asm volatile("s_waitcnt vmcnt(3)" ::: "memory");
    else if constexpr (N == 4) asm volatile("s_waitcnt vmcnt(4)" ::: "memory");
    else if constexpr (N == 6) asm volatile("s_waitcnt vmcnt(6)" ::: "memory");
}

__device__ __forceinline__ void bar() {
    __builtin_amdgcn_s_barrier();
    asm volatile("" ::: "memory");
}

__device__ __forceinline__ float bf2f(short s) {
    __hip_bfloat16 h;
    *reinterpret_cast<short*>(&h) = s;
    return __bfloat162float(h);
}
__device__ __forceinline__ short f2bf(float f) {
    __hip_bfloat16 h = __float2bfloat16(f);
    return *reinterpret_cast<short*>(&h);
}

// ---------------- bf16 MFMA GEMM: C = A @ Bt^T + epilogue ----------------
// A: [MP][K] bf16 row-major. Bt: [N][K] bf16 (weights pre-transposed).
// Double-buffered gl2lds staging with counted vmcnt (never 0 mid-loop).
// BM in {32,64}: 64 -> 2x2 waves of 32x32; 32 -> 1x4 waves of 32x16.
// EPI: 1 = bias -> Cf
//      3 = QKV+RL: col<1536 bias -> Cb (stride 1536); col>=1536 -> Cf f32 rl[row*64+col-1536]
//      4 = bias+res -> Cf(f32) + Cb(bf16)
//      5 = bias+res -> Cf(f32) AND Cb(bf16) + per-row (sum,sumsq) atomics -> stats
//      6 = epilogue-LN + gelu -> Cb:  v = rinv*acc - mean*rinv*aux[col] + bias[col]
template<int EPI, int BM>
__global__ __launch_bounds__(256)
void mgemm(const __hip_bfloat16* __restrict__ A, const __hip_bfloat16* __restrict__ Bt,
           const float* __restrict__ bias, const float* __restrict__ res,
           float* __restrict__ Cf, __hip_bfloat16* __restrict__ Cb,
           float* __restrict__ stats, const float* __restrict__ aux,
           int M, int N, int K)
{
    constexpr int ACH  = BM * 8;          // A tile 16B-chunks
    constexpr int ABYT = BM * 128;        // A tile bytes
    constexpr int STG  = ABYT + 8192;     // bytes per buffer (A + B)
    constexpr int LPT  = (ACH + 512) / 256; // gl2lds per thread per stage (4 or 3)
    constexpr int NI   = (BM == 64) ? 2 : 1;
    __shared__ char lds[2 * STG];
    const int tid = threadIdx.x;
    const int bm = blockIdx.y * BM, bn = blockIdx.x << 6;
    const int lane = tid & 63, wv = tid >> 6;
    const int wm = (BM == 64) ? ((wv & 1) << 5) : 0;
    const int wn = (BM == 64) ? ((wv >> 1) << 5) : (wv << 4);
    const int fr = lane & 15, kg = lane >> 4;

    int offA[2][2], offB[2][2];
    #pragma unroll
    for (int mi = 0; mi < 2; ++mi)
        #pragma unroll
        for (int kk = 0; kk < 2; ++kk) {
            int kb = (kk << 6) + (kg << 4);
            int ra = wm + (mi << 4) + fr;
            offA[mi][kk] = (ra << 7) + (kb ^ ((ra & 7) << 4));
        }
    #pragma unroll
    for (int ni = 0; ni < NI; ++ni)
        #pragma unroll
        for (int kk = 0; kk < 2; ++kk) {
            int kb = (kk << 6) + (kg << 4);
            int rb = wn + (ni << 4) + fr;
            offB[ni][kk] = ABYT + (rb << 7) + (kb ^ ((rb & 7) << 4));
        }

    auto stage = [&](int sb, int k0) {
        char* base = lds + sb * STG;
        #pragma unroll
        for (int c = 0; c < ACH / 256; ++c) {
            int idx = c * 256 + tid;
            int row = idx >> 3, kb = (idx & 7) << 4;
            gl2lds16((const char*)A + (((size_t)(bm + row) * K + k0) << 1) + (kb ^ ((row & 7) << 4)),
                     base + idx * 16);
        }
        #pragma unroll
        for (int c = 0; c < 2; ++c) {
            int idx = c * 256 + tid;
            int row = idx >> 3, kb = (idx & 7) << 4;
            gl2lds16((const char*)Bt + (((size_t)(bn + row) * K + k0) << 1) + (kb ^ ((row & 7) << 4)),
                     base + ABYT + idx * 16);
        }
    };

    f32x4 acc[2][2] = {};
    const int NK = K >> 6;
    stage(0, 0);
    for (int ks = 0; ks < NK; ++ks) {
        const int cur = ks & 1;
        if (ks + 1 < NK) { stage(cur ^ 1, (ks + 1) << 6); vmw<LPT>(); }
        else vmw<0>();
        bar();                               // stage ks data visible in LDS
        const char* bp = lds + cur * STG;
        bf16x8 af[2][2], bf_[2][2];
        #pragma unroll
        for (int mi = 0; mi < 2; ++mi)
            #pragma unroll
            for (int kk = 0; kk < 2; ++kk)
                af[mi][kk] = *(const bf16x8*)(bp + offA[mi][kk]);
        #pragma unroll
        for (int ni = 0; ni < NI; ++ni)
            #pragma unroll
            for (int kk = 0; kk < 2; ++kk)
                bf_[ni][kk] = *(const bf16x8*)(bp + offB[ni][kk]);
        #pragma unroll
        for (int kk = 0; kk < 2; ++kk)
            #pragma unroll
            for (int mi = 0; mi < 2; ++mi)
                #pragma unroll
                for (int ni = 0; ni < NI; ++ni)
                    acc[mi][ni] = __builtin_amdgcn_mfma_f32_16x16x32_bf16(
                        af[mi][kk], bf_[ni][kk], acc[mi][ni], 0, 0, 0);
        asm volatile("s_waitcnt lgkmcnt(0)" ::: "memory");
        bar();                               // buf[cur] reusable next+1 iter
    }

    const int rb4 = kg << 2;
    float b_[NI], w_[NI];
    #pragma unroll
    for (int ni = 0; ni < NI; ++ni) {
        int col = bn + wn + (ni << 4) + fr;
        b_[ni] = bias[col];
        if (EPI == 6) w_[ni] = aux[col];
    }
    #pragma unroll
    for (int mi = 0; mi < 2; ++mi)
        #pragma unroll
        for (int r = 0; r < 4; ++r) {
            const int row = bm + wm + (mi << 4) + rb4 + r;
            if (row >= M) continue;          // uniform over fr-group
            float mean = 0.f, rinv = 0.f;
            if (EPI == 6) {
                float s0 = stats[row * 2 + 0], s1 = stats[row * 2 + 1];
                mean = s0 * (1.f / 512.f);
                rinv = rsqrtf(s1 * (1.f / 512.f) - mean * mean + EPSLN);
            }
            float vs = 0.f, vq = 0.f;
            #pragma unroll
            for (int ni = 0; ni < NI; ++ni) {
                const int col = bn + wn + (ni << 4) + fr;
                float v = acc[mi][ni][r];
                if (EPI == 6) v = rinv * v - mean * rinv * w_[ni] + b_[ni];
                else v += b_[ni];
                if (EPI == 4 || EPI == 5) v += res[(size_t)row * N + col];
                if (EPI == 6) {
                    float g = 0.5f * v * (1.f + tanhf(0.7978845608028654f * (v + 0.044715f * v * v * v)));
                    Cb[(size_t)row * N + col] = __float2bfloat16(g);
                } else if (EPI == 3) {
                    if (col < 1536) Cb[(size_t)row * 1536 + col] = __float2bfloat16(v);
                    else            Cf[(size_t)row * 64 + (col - 1536)] = v;
                } else if (EPI == 4) {
                    Cf[(size_t)row * N + col] = v;
                    Cb[(size_t)row * N + col] = __float2bfloat16(v);
                } else if (EPI == 5) {
                    Cf[(size_t)row * N + col] = v;
                    Cb[(size_t)row * N + col] = __float2bfloat16(v);
                    vs += v; vq += v * v;
                } else {
                    Cf[(size_t)row * N + col] = v;
                }
            }
            if (EPI == 5) {
                #pragma unroll
                for (int m2 = 1; m2 < 16; m2 <<= 1) {
                    vs += __shfl_xor(vs, m2);
                    vq += __shfl_xor(vq, m2);
                }
                if (fr == 0) {
                    atomicAdd(&stats[row * 2 + 0], vs);
                    atomicAdd(&stats[row * 2 + 1], vq);
                }
            }
        }
}

// ---------------- halting GEMM: z[row][0:2] += tanh(chi@Wh1+bh1) @ Wh2 ----------------
// Plain bf16. N=K=512 fixed. BM=32, double-buffered.
__global__ __launch_bounds__(256)
void halt_gemm(const __hip_bfloat16* __restrict__ Ahp, const __hip_bfloat16* __restrict__ Bhp,
               const float* __restrict__ bh1, const float* __restrict__ Wh2,
               float* __restrict__ z, int M)
{
    constexpr int STG = 12288;   // Ah 4K @0, Bh 8K @4096
    __shared__ char lds[2 * STG];
    const int tid = threadIdx.x;
    const int bm = blockIdx.y << 5, bn = blockIdx.x << 6;
    const int lane = tid & 63, wv = tid >> 6;
    const int wn = wv << 4;
    const int fr = lane & 15, kg = lane >> 4;

    int offA[2][2], offB[2];
    #pragma unroll
    for (int mi = 0; mi < 2; ++mi)
        #pragma unroll
        for (int kk = 0; kk < 2; ++kk) {
            int kb = (kk << 6) + (kg << 4);
            int ra = (mi << 4) + fr;
            offA[mi][kk] = (ra << 7) + (kb ^ ((ra & 7) << 4));
        }
    #pragma unroll
    for (int kk = 0; kk < 2; ++kk) {
        int kb = (kk << 6) + (kg << 4);
        int rb = wn + fr;
        offB[kk] = 4096 + (rb << 7) + (kb ^ ((rb & 7) << 4));
    }

    auto stage = [&](int sb, int k0) {
        char* base = lds + sb * STG;
        {
            int row = tid >> 3, kb = (tid & 7) << 4;
            int swz = kb ^ ((row & 7) << 4);
            size_t aoff = (((size_t)(bm + row) * 512 + k0) << 1) + swz;
            gl2lds16((const char*)Ahp + aoff, base + tid * 16);
        }
        #pragma unroll
        for (int c = 0; c < 2; ++c) {
            int idx = c * 256 + tid;
            int row = idx >> 3, kb = (idx & 7) << 4;
            int swz = kb ^ ((row & 7) << 4);
            size_t boff = (((size_t)(bn + row) * 512 + k0) << 1) + swz;
            gl2lds16((const char*)Bhp + boff, base + 4096 + idx * 16);
        }
    };

    f32x4 acc[2] = {};
    stage(0, 0);
    for (int ks = 0; ks < 8; ++ks) {
        const int cur = ks & 1;
        if (ks < 7) { stage(cur ^ 1, (ks + 1) << 6); vmw<3>(); }
        else vmw<0>();
        bar();
        const char* bp = lds + cur * STG;
        bf16x8 ah[2][2], bh_[2];
        #pragma unroll
        for (int mi = 0; mi < 2; ++mi)
            #pragma unroll
            for (int kk = 0; kk < 2; ++kk)
                ah[mi][kk] = *(const bf16x8*)(bp + offA[mi][kk]);
        #pragma unroll
        for (int kk = 0; kk < 2; ++kk)
            bh_[kk] = *(const bf16x8*)(bp + offB[kk]);
        #pragma unroll
        for (int kk = 0; kk < 2; ++kk)
            #pragma unroll
            for (int mi = 0; mi < 2; ++mi)
                acc[mi] = __builtin_amdgcn_mfma_f32_16x16x32_bf16(ah[mi][kk], bh_[kk], acc[mi], 0, 0, 0);
        asm volatile("s_waitcnt lgkmcnt(0)" ::: "memory");
        bar();
    }

    const int col = bn + wn + fr;
    const float b_ = bh1[col];
    const float w0_ = Wh2[col * 2 + 0];
    const float w1_ = Wh2[col * 2 + 1];
    #pragma unroll
    for (int mi = 0; mi < 2; ++mi)
        #pragma unroll
        for (int r = 0; r < 4; ++r) {
            float v = tanhf(acc[mi][r] + b_);
            float p0 = v * w0_;
            float p1 = v * w1_;
            #pragma unroll
            for (int m2 = 1; m2 < 16; m2 <<= 1) {
                p0 += __shfl_xor(p0, m2);
                p1 += __shfl_xor(p1, m2);
            }
            if (fr == 0) {
                int row = bm + (mi << 4) + (kg << 2) + r;
                if (row < M) {
                    atomicAdd(&z[row * 2 + 0], p0);
                    atomicAdd(&z[row * 2 + 1], p1);
                }
            }
        }
}

// ---------------- MFMA attention ----------------
// grid (5 q-chunks, 8 heads, 16 batch), 256 threads. Q/K/V from bf16 qkvb; rel
// logits precomputed into rl[MP][64] (h*8+c) by the QKV GEMM. Two-barrier
// distributed in-register softmax (round-10 proven); P aliases the dead KT region.
#define KT_BASE 0          // [144][128B] XOR-swizzled K (B-layout)   18432
#define P_BASE  0          // [32][336B] bf16 softmax — ALIASES KT    10752
#define VT_BASE 18432      // [64][384B] XOR-swizzled V^T             24576
#define QC_BASE 43008      // [32][72] bf16 q+cb (stride 144B)         4608
#define R_BASE  47616      // [32][8] f32 rel logits                   1024
#define WM_BASE 48640      // [4][32] f32 per-wave row max              512
#define WS_BASE 49152      // [4][32] f32 per-wave row sum              512
__global__ __launch_bounds__(256)
void attn_mfma(const __hip_bfloat16* __restrict__ qkvb,
               const float* __restrict__ rl, const float* __restrict__ cbias,
               __hip_bfloat16* __restrict__ aout)
{
    __shared__ char lds[49664];
    const int tid = threadIdx.x;
    const int chunk = blockIdx.x, hh = blockIdx.y, b = blockIdx.z;
    const int q0 = chunk << 5;
    const int lane = tid & 63, wv = tid >> 6;
    const int fr = lane & 15, kg = lane >> 4;
    const size_t qrow0 = (size_t)b * Sc;
    const short* qs = (const short*)qkvb;

    // phase 0: zero VT (full 24576B) + Kt pad rows 129..143
    {
        f32x4 zz = {};
        #pragma unroll
        for (int i = 0; i < 6; ++i)
            *(f32x4*)(lds + VT_BASE + (i * 256 + tid) * 16) = zz;
        if (tid < 120)
            *(f32x4*)(lds + KT_BASE + 129 * 128 + tid * 16) = zz;
    }
    __syncthreads();

    // stage Kt (rows 0..128) via global_load_lds, XOR pre-swizzled source
    #pragma unroll
    for (int i = 0; i < 5; ++i) {
        int idx = i * 256 + tid;
        if (idx < 1152) {
            int row = idx >> 3, ch = idx & 7;
            if (row <= 128) {
                const char* src = (const char*)qkvb +
                    (((qrow0 + row) * 1536 + 512 + (size_t)hh * 64) << 1) + ((ch ^ (row & 7)) << 4);
                gl2lds16(src, lds + KT_BASE + idx * 16);
            }
        }
    }
    // stage V^T: swizzled scatter writes (conflict-free by key=(g^j))
    #pragma unroll
    for (int i = 0; i < 5; ++i) {
        int idx = i * 256 + tid;
        if (idx < 1032) {                    // 129 T-slots x 8 d-groups
            int T = idx >> 3, g = idx & 7;
            bf16x8 v = *(const bf16x8*)(qs + (qrow0 + T) * 1536 + 1024 + hh * 64 + g * 8);
            #pragma unroll
            for (int j = 0; j < 8; ++j) {
                int row = g * 8 + j;
                int key = (g ^ j) & 7;
                *(short*)(lds + VT_BASE + row * 384 + ((T * 2) ^ (key << 4))) = v[j];
            }
        }
    }
    // stage Qc = bf16(q + content_bias): 256 threads = 32 rows x 8 groups
    {
        int row = tid >> 3, g = tid & 7;
        bf16x8 q8 = *(const bf16x8*)(qs + (qrow0 + q0 + row) * 1536 + hh * 64 + g * 8);
        const float* cb = cbias + hh * 64 + g * 8;
        bf16x8 o8;
        #pragma unroll
        for (int j = 0; j < 8; ++j)
            o8[j] = f2bf(bf2f(q8[j]) + cb[j]);
        *(bf16x8*)(lds + QC_BASE + row * 144 + g * 16) = o8;
    }
    // R[row][c]: precomputed rel logits, coalesced f32 load
    if (tid < 224) {
        int row = tid / 7, c = tid % 7;
        *(float*)(lds + R_BASE + (row * 8 + c) * 4) =
            rl[(qrow0 + q0 + row) * 64 + hh * 8 + c];
    }
    __syncthreads();

    // QK^T: 9 N-tiles over 4 waves
    f32x4 acc[2][3] = {};
    __builtin_amdgcn_s_setprio(1);
    #pragma unroll
    for (int ni = 0; ni < 3; ++ni) {
        int nt = wv + ni * 4;
        if (nt > 8) continue;
        #pragma unroll
        for (int mt = 0; mt < 2; ++mt)
            #pragma unroll
            for (int ks = 0; ks < 2; ++ks) {
                bf16x8 a = *(const bf16x8*)(lds + QC_BASE + (mt * 16 + fr) * 144 + ks * 64 + kg * 16);
                int rowb = nt * 16 + fr;
                bf16x8 bb = *(const bf16x8*)(lds + KT_BASE + rowb * 128 +
                                             ((ks * 64 + kg * 16) ^ ((rowb & 7) << 4)));
                acc[mt][ni] = __builtin_amdgcn_mfma_f32_16x16x32_bf16(a, bb, acc[mt][ni], 0, 0, 0);
            }
    }
    __builtin_amdgcn_s_setprio(0);

    // s = (cl + rl)*scale, masked — in registers (overwrite acc)
    #pragma unroll
    for (int ni = 0; ni < 3; ++ni) {
        int nt = wv + ni * 4;
        int col = nt * 16 + fr;
        #pragma unroll
        for (int mt = 0; mt < 2; ++mt)
            #pragma unroll
            for (int r = 0; r < 4; ++r) {
                int row = mt * 16 + kg * 4 + r;
                float sv = -1e30f;
                if (nt <= 8 && col <= 128) {
                    int delta = q0 + row - col;
                    int c = delta >= 3 ? 3 : (delta <= -3 ? 4 : (delta < 0 ? delta + 7 : delta));
                    float rlv = *(const float*)(lds + R_BASE + (row * 8 + c) * 4);
                    sv = (acc[mt][ni][r] + rlv) * 0.125f;
                }
                acc[mt][ni][r] = sv;
            }
    }

    // distributed row max: in-lane (ni) + fr-group shfl + per-wave partials in LDS
    float m_[2][4];
    #pragma unroll
    for (int mt = 0; mt < 2; ++mt)
        #pragma unroll
        for (int r = 0; r < 4; ++r) {
            float m = fmaxf(fmaxf(acc[mt][0][r], acc[mt][1][r]), acc[mt][2][r]);
            #pragma unroll
            for (int b2 = 1; b2 < 16; b2 <<= 1) m = fmaxf(m, __shfl_xor(m, b2));
            m_[mt][r] = m;
        }
    if (fr == 0) {
        float* wm = (float*)(lds + WM_BASE) + (wv << 5);
        #pragma unroll
        for (int mt = 0; mt < 2; ++mt)
            #pragma unroll
            for (int r = 0; r < 4; ++r)
                wm[mt * 16 + (kg << 2) + r] = m_[mt][r];
    }
    __syncthreads();                        // bar1: all KT reads complete; P region free

    // zero P cols 144..159 (32 rows x 32B), safe after bar1
    if (tid < 128) {
        int row = tid >> 2;
        *(double*)(lds + P_BASE + row * 336 + 288 + (tid & 3) * 8) = 0.0;
    }

    // global max per row; exp; lane sums
    const float* wm = (const float*)(lds + WM_BASE);
    float gm[2][4], su[2][4];
    #pragma unroll
    for (int mt = 0; mt < 2; ++mt)
        #pragma unroll
        for (int r = 0; r < 4; ++r) {
            int row = mt * 16 + (kg << 2) + r;
            float g0 = fmaxf(wm[row], wm[32 + row]);
            float g1 = fmaxf(wm[64 + row], wm[96 + row]);
            gm[mt][r] = fmaxf(g0, g1);
            su[mt][r] = 0.f;
        }
    #pragma unroll
    for (int ni = 0; ni < 3; ++ni)
        #pragma unroll
        for (int mt = 0; mt < 2; ++mt)
            #pragma unroll
            for (int r = 0; r < 4; ++r) {
                float s = acc[mt][ni][r];
                float e = (s > -1e29f) ? expf(s - gm[mt][r]) : 0.f;
                acc[mt][ni][r] = e;
                su[mt][r] += e;
            }
    #pragma unroll
    for (int mt = 0; mt < 2; ++mt)
        #pragma unroll
        for (int r = 0; r < 4; ++r) {
            float s = su[mt][r];
            #pragma unroll
            for (int b2 = 1; b2 < 16; b2 <<= 1) s += __shfl_xor(s, b2);
            su[mt][r] = s;
        }
    if (fr == 0) {
        float* ws = (float*)(lds + WS_BASE) + (wv << 5);
        #pragma unroll
        for (int mt = 0; mt < 2; ++mt)
            #pragma unroll
            for (int r = 0; r < 4; ++r)
                ws[mt * 16 + (kg << 2) + r] = su[mt][r];
    }
    __syncthreads();                        // bar2

    const float* wsm = (const float*)(lds + WS_BASE);
    float inv_[2][4];
    #pragma unroll
    for (int mt = 0; mt < 2; ++mt)
        #pragma unroll
        for (int r = 0; r < 4; ++r) {
            int row = mt * 16 + (kg << 2) + r;
            float t = (wsm[row] + wsm[32 + row]) + (wsm[64 + row] + wsm[96 + row]);
            inv_[mt][r] = 1.f / t;
        }
    // P write (bf16) into aliased KT region
    #pragma unroll
    for (int ni = 0; ni < 3; ++ni) {
        int nt = wv + ni * 4;
        if (nt > 8) continue;
        int col = nt * 16 + fr;
        #pragma unroll
        for (int mt = 0; mt < 2; ++mt)
            #pragma unroll
            for (int r = 0; r < 4; ++r) {
                int row = mt * 16 + (kg << 2) + r;
                *(short*)(lds + P_BASE + row * 336 + col * 2) =
                    f2bf(acc[mt][ni][r] * inv_[mt][r]);
            }
    }
    __syncthreads();                        // bar3

    // PV: wave owns 16 output dims; V^T read with matching XOR swizzle
    f32x4 acc2[2] = {};
    const int rowv = wv * 16 + fr;
    const int keyv = ((rowv >> 3) ^ rowv) & 7;
    __builtin_amdgcn_s_setprio(1);
    #pragma unroll
    for (int mt = 0; mt < 2; ++mt)
        #pragma unroll
        for (int ks = 0; ks < 5; ++ks) {
            bf16x8 a  = *(const bf16x8*)(lds + P_BASE + (mt * 16 + fr) * 336 + ks * 64 + kg * 16);
            bf16x8 bb = *(const bf16x8*)(lds + VT_BASE + rowv * 384 +
                                         ((ks * 64 + kg * 16) ^ (keyv << 4)));
            acc2[mt] = __builtin_amdgcn_mfma_f32_16x16x32_bf16(a, bb, acc2[mt], 0, 0, 0);
        }
    __builtin_amdgcn_s_setprio(0);
    #pragma unroll
    for (int mt = 0; mt < 2; ++mt)
        #pragma unroll
        for (int r = 0; r < 4; ++r) {
            int t = q0 + mt * 16 + kg * 4 + r;
            if (t <= 128)
                aout[(qrow0 + t) * 512 + hh * 64 + wv * 16 + fr] = __float2bfloat16(acc2[mt][r]);
        }
}

// ---------------- ACT bookkeeping + LN(curr) + blend + h_out ----------------
// 4 rows per block, one 64-lane wave per row; no LDS, no syncthreads.
__global__ __launch_bounds__(256)
void haltblend(const float* __restrict__ curr, const float* __restrict__ s,
               const float* __restrict__ o, float* __restrict__ zbuf,
               float* __restrict__ lanh, float* __restrict__ lah,
               float* __restrict__ h, __hip_bfloat16* __restrict__ hb,
               float* __restrict__ hout, float* __restrict__ stats)
{
    const int row = (blockIdx.x << 2) + (threadIdx.x >> 6);
    const int lane = threadIdx.x & 63;

    float z0 = zbuf[row * 2 + 0] + 2.f;
    float z1 = zbuf[row * 2 + 1] - 2.f;
    float mxz = fmaxf(z0, z1);
    float lse = mxz + logf(expf(z0 - mxz) + expf(z1 - mxz));
    float lg0 = z0 - lse, lg1 = z1 - lse;
    float ln_ = lanh[row], la_ = lah[row];
    float lhalt = ln_ + lg1;
    float hl = expf(la_);            // PRE-update lah
    float ph = expf(lhalt);

    const size_t rbase = (size_t)row * 512;
    const int c0 = lane << 3;
    f32x4 x0 = *(const f32x4*)(curr + rbase + c0);
    f32x4 x1 = *(const f32x4*)(curr + rbase + c0 + 4);
    float sum = (x0[0] + x0[1]) + (x0[2] + x0[3]) + (x1[0] + x1[1]) + (x1[2] + x1[3]);
    float sq  = (x0[0] * x0[0] + x0[1] * x0[1]) + (x0[2] * x0[2] + x0[3] * x0[3])
              + (x1[0] * x1[0] + x1[1] * x1[1]) + (x1[2] * x1[2] + x1[3] * x1[3]);
    #pragma unroll
    for (int m2 = 1; m2 < 64; m2 <<= 1) { sum += __shfl_xor(sum, m2); sq += __shfl_xor(sq, m2); }
    float mean = sum * (1.f / 512.f);
    float inv = rsqrtf(sq * (1.f / 512.f) - mean * mean + EPSLN);

    if (lane == 0) {
        lanh[row] = ln_ + lg0;
        float m3 = fmaxf(la_, lhalt);
        lah[row] = m3 + logf(expf(la_ - m3) + expf(lhalt - m3));
        zbuf[row * 2 + 0] = 0.f;
        zbuf[row * 2 + 1] = 0.f;
        stats[row * 2 + 0] = 0.f;    // reset LN stats for next iteration's Wo epilogue
        stats[row * 2 + 1] = 0.f;
    }

    f32x4 sv0 = *(const f32x4*)(s + c0), sv1 = *(const f32x4*)(s + c0 + 4);
    f32x4 ov0 = *(const f32x4*)(o + c0), ov1 = *(const f32x4*)(o + c0 + 4);
    f32x4 hv0 = *(f32x4*)(h + rbase + c0), hv1 = *(f32x4*)(h + rbase + c0 + 4);
    f32x4 ho0 = *(f32x4*)(hout + rbase + c0), ho1 = *(f32x4*)(hout + rbase + c0 + 4);
    u16x4 hb0, hb1;
    #pragma unroll
    for (int e = 0; e < 4; ++e) {
        float cl = (x0[e] - mean) * inv * sv0[e] + ov0[e];
        float hn = hl * hv0[e] + (1.f - hl) * cl;
        hv0[e] = hn;
        __hip_bfloat16 bb = __float2bfloat16(hn);
        hb0[e] = *reinterpret_cast<unsigned short*>(&bb);
        ho0[e] += ph * cl;
    }
    #pragma unroll
    for (int e = 0; e < 4; ++e) {
        float cl = (x1[e] - mean) * inv * sv1[e] + ov1[e];
        float hn = hl * hv1[e] + (1.f - hl) * cl;
        hv1[e] = hn;
        __hip_bfloat16 bb = __float2bfloat16(hn);
        hb1[e] = *reinterpret_cast<unsigned short*>(&bb);
        ho1[e] += ph * cl;
    }
    *(f32x4*)(h + rbase + c0) = hv0;
    *(f32x4*)(h + rbase + c0 + 4) = hv1;
    *(u16x4*)(reinterpret_cast<unsigned short*>(hb) + rbase + c0) = hb0;
    *(u16x4*)(reinterpret_cast<unsigned short*>(hb) + rbase + c0 + 4) = hb1;
    *(f32x4*)(hout + rbase + c0) = ho0;
    *(f32x4*)(hout + rbase + c0 + 4) = ho1;
}

// ---------------- setup kernels ----------------
__global__ __launch_bounds__(256)
void emb_kernel(const float* __restrict__ x, const float* __restrict__ We,
                const float* __restrict__ eos, const float* __restrict__ s,
                const float* __restrict__ o, float* __restrict__ h,
                __hip_bfloat16* __restrict__ hb)
{
    int row = blockIdx.x, tid = threadIdx.x;
    int b = row / Sc, t = row % Sc;
    __shared__ float xs[64];
    if (t != 128 && tid < 64) xs[tid] = x[((size_t)b * 128 + t) * 64 + tid];
    __syncthreads();
    float v0, v1;
    if (t == 128) {
        v0 = eos[tid]; v1 = eos[tid + 256];
    } else {
        v0 = 0.f; v1 = 0.f;
        #pragma unroll 8
        for (int k = 0; k < 64; ++k) {
            float xv = xs[k];
            v0 = fmaf(xv, We[k * 512 + tid], v0);
            v1 = fmaf(xv, We[k * 512 + tid + 256], v1);
        }
    }
    float sum = v0 + v1, sq = v0 * v0 + v1 * v1;
    #pragma unroll
    for (int m2 = 1; m2 < 64; m2 <<= 1) { sum += __shfl_xor(sum, m2); sq += __shfl_xor(sq, m2); }
    __shared__ float ssum[4], ssq[4];
    if ((tid & 63) == 0) { ssum[tid >> 6] = sum; ssq[tid >> 6] = sq; }
    __syncthreads();
    float tot = ssum[0] + ssum[1] + ssum[2] + ssum[3];
    float totq = ssq[0] + ssq[1] + ssq[2] + ssq[3];
    float mean = tot * (1.f / 512.f);
    float inv = rsqrtf(totq * (1.f / 512.f) - mean * mean + EPSLN);
    float h0 = (v0 - mean) * inv * s[tid] + o[tid];
    float h1 = (v1 - mean) * inv * s[tid + 256] + o[tid + 256];
    h[(size_t)row * 512 + tid] = h0;
    h[(size_t)row * 512 + tid + 256] = h1;
    hb[(size_t)row * 512 + tid] = __float2bfloat16(h0);
    hb[(size_t)row * 512 + tid + 256] = __float2bfloat16(h1);
}

__global__ __launch_bounds__(256)
void rk7_kernel(const float* __restrict__ pos, const float* __restrict__ Wk,
                const float* __restrict__ bk, float* __restrict__ rk7)
{
    int c = blockIdx.x, tid = threadIdx.x;
    __shared__ float ps[512];
    ps[tid] = pos[c * 512 + tid];
    ps[tid + 256] = pos[c * 512 + tid + 256];
    __syncthreads();
    float a0 = bk[tid], a1 = bk[tid + 256];
    for (int k = 0; k < 512; ++k) {
        float pv = ps[k];
        a0 = fmaf(pv, Wk[(size_t)k * 512 + tid], a0);
        a1 = fmaf(pv, Wk[(size_t)k * 512 + tid + 256], a1);
    }
    rk7[c * 512 + tid] = a0;
    rk7[c * 512 + tid + 256] = a1;
}

__global__ __launch_bounds__(256)
void pack_qkvT(const float* __restrict__ Wq, const float* __restrict__ Wk,
               const float* __restrict__ Wv, __hip_bfloat16* __restrict__ Wt)
{
    int idx = blockIdx.x * 256 + threadIdx.x;
    if (idx >= 1536 * 512) return;
    int n = idx >> 9, k = idx & 511;
    const float* src = (n < 512) ? Wq : (n < 1024) ? Wk : Wv;
    int nc = n & 511;
    Wt[idx] = __float2bfloat16(src[(size_t)k * 512 + nc]);
}

// Append rl weights: Wt[1536 + h*8+c][k] = bf16( sum_d Wq[k][h*64+d]*rk7[c][h*64+d] )
// and bias bqkv[1536 + h*8+c] = sum_d (bq+rbias)[h*64+d]*rk7[c][h*64+d]. c==7 -> 0 pad.
__global__ __launch_bounds__(256)
void fold_rl(const float* __restrict__ Wq, const float* __restrict__ bq,
             const float* __restrict__ rbias, const float* __restrict__ rk7,
             __hip_bfloat16* __restrict__ Wt, float* __restrict__ bqkv)
{
    int idx = blockIdx.x * 256 + threadIdx.x;
    if (idx >= 64 * 512) return;
    int n = idx >> 9, k = idx & 511;
    int hh = n >> 3, c = n & 7;
    float a = 0.f;
    if (c < 7) {
        #pragma unroll 8
        for (int d = 0; d < 64; ++d)
            a = fmaf(Wq[(size_t)k * 512 + hh * 64 + d], rk7[c * 512 + hh * 64 + d], a);
    }
    Wt[(size_t)(1536 + n) * 512 + k] = __float2bfloat16(a);
    if (idx < 64) {
        int hh2 = idx >> 3, c2 = idx & 7;
        float s = 0.f;
        if (c2 < 7) {
            for (int d = 0; d < 64; ++d)
                s = fmaf(bq[hh2 * 64 + d] + rbias[hh2 * 64 + d], rk7[c2 * 512 + hh2 * 64 + d], s);
        }
        bqkv[1536 + idx] = s;
    }
}

__global__ __launch_bounds__(256)
void transposeT(const float* __restrict__ W, __hip_bfloat16* __restrict__ Wt, int K, int N)
{
    int idx = blockIdx.x * 256 + threadIdx.x;
    if (idx >= K * N) return;
    int n = idx / K, k = idx - n * K;
    Wt[idx] = __float2bfloat16(W[(size_t)k * N + n]);
}

// Wt[n][k] = bf16(W[k][n] * s[k])   (fold LN scale into W1)
__global__ __launch_bounds__(256)
void transposeT_scale(const float* __restrict__ W, const float* __restrict__ s,
                      __hip_bfloat16* __restrict__ Wt, int K, int N)
{
    int idx = blockIdx.x * 256 + threadIdx.x;
    if (idx >= K * N) return;
    int n = idx / K, k = idx - n * K;
    Wt[idx] = __float2bfloat16(W[(size_t)k * N + n] * s[k]);
}

// w1sum[n] = sum_k s[k]*W[k][n];  b1f[n] = b[n] + sum_k o[k]*W[k][n]
__global__ __launch_bounds__(256)
void fold_w1(const float* __restrict__ W, const float* __restrict__ s,
             const float* __restrict__ o, const float* __restrict__ b,
             float* __restrict__ w1sum, float* __restrict__ b1f, int K, int N)
{
    int n = blockIdx.x * 256 + threadIdx.x;
    if (n >= N) return;
    float ws = 0.f, bo_ = b[n];
    for (int k = 0; k < K; ++k) {
        float w = W[(size_t)k * N + n];
        ws = fmaf(s[k], w, ws);
        bo_ = fmaf(o[k], w, bo_);
    }
    w1sum[n] = ws;
    b1f[n] = bo_;
}

__global__ __launch_bounds__(256)
void pack_bias(const float* __restrict__ bq, const float* __restrict__ bk,
               const float* __restrict__ bv, float* __restrict__ bqkv)
{
    int idx = blockIdx.x * 256 + threadIdx.x;
    if (idx < 1536)
        bqkv[idx] = (idx < 512) ? bq[idx] : (idx < 1024) ? bk[idx - 512] : bv[idx - 1024];
}

__global__ __launch_bounds__(256)
void init_kernel(float* __restrict__ lanh, float* __restrict__ lah,
                 float* __restrict__ zbuf, float* __restrict__ stats)
{
    int idx = blockIdx.x * 256 + threadIdx.x;
    if (idx < Mc) {
        lanh[idx] = 0.f; lah[idx] = -64.f;
        zbuf[idx * 2 + 0] = 0.f; zbuf[idx * 2 + 1] = 0.f;
    }
    if (idx < MP) {
        stats[idx * 2 + 0] = 0.f; stats[idx * 2 + 1] = 0.f;
    }
}

// ---------------- host launcher ----------------
extern "C" void kernel_launch(void* const* d_in, const int* in_sizes, int n_in,
                              void* d_out, int out_size, void* d_ws, size_t ws_size,
                              hipStream_t stream)
{
    const float* x     = (const float*)d_in[0];
    const float* We    = (const float*)d_in[1];
    const float* eos   = (const float*)d_in[2];
    const float* Wq    = (const float*)d_in[3];
    const float* bq    = (const float*)d_in[4];
    const float* Wk    = (const float*)d_in[5];
    const float* bk    = (const float*)d_in[6];
    const float* Wv    = (const float*)d_in[7];
    const float* bv    = (const float*)d_in[8];
    const float* Wo    = (const float*)d_in[9];
    const float* bo    = (const float*)d_in[10];
    const float* cbias = (const float*)d_in[11];
    const float* rbias = (const float*)d_in[12];
    const float* pos   = (const float*)d_in[13];
    const float* ln2s  = (const float*)d_in[14];
    const float* ln2o  = (const float*)d_in[15];
    const float* lnos  = (const float*)d_in[16];
    const float* lnoo  = (const float*)d_in[17];
    const float* W1    = (const float*)d_in[18];
    const float* b1    = (const float*)d_in[19];
    const float* W2    = (const float*)d_in[20];
    const float* b2    = (const float*)d_in[21];
    const float* Wh1   = (const float*)d_in[22];
    const float* bh1   = (const float*)d_in[23];
    const float* Wh2   = (const float*)d_in[24];
    (void)in_sizes; (void)n_in; (void)ws_size;

    char* wp = (char*)d_ws;
    auto alloc = [&](size_t bytes) { char* p = wp; wp += (bytes + 255) & ~(size_t)255; return p; };
    float*          h     = (float*)alloc((size_t)MP * 512 * 4);
    __hip_bfloat16* hb    = (__hip_bfloat16*)alloc((size_t)MP * 512 * 2);
    __hip_bfloat16* qkvb  = (__hip_bfloat16*)alloc((size_t)MP * 1536 * 2);
    float*          rlb   = (float*)alloc((size_t)MP * 64 * 4);
    __hip_bfloat16* abufb = (__hip_bfloat16*)alloc((size_t)MP * 512 * 2);
    float*          hmid  = (float*)alloc((size_t)MP * 512 * 4);
    __hip_bfloat16* hmidb = (__hip_bfloat16*)alloc((size_t)MP * 512 * 2);
    __hip_bfloat16* g1b   = (__hip_bfloat16*)alloc((size_t)MP * 1024 * 2);
    float*          curr  = (float*)alloc((size_t)MP * 512 * 4);
    __hip_bfloat16* chi   = (__hip_bfloat16*)alloc((size_t)MP * 512 * 2);
    __hip_bfloat16* WqkvT = (__hip_bfloat16*)alloc((size_t)1600 * 512 * 2);
    __hip_bfloat16* WoT   = (__hip_bfloat16*)alloc((size_t)512 * 512 * 2);
    __hip_bfloat16* W1T   = (__hip_bfloat16*)alloc((size_t)1024 * 512 * 2);
    __hip_bfloat16* W2T   = (__hip_bfloat16*)alloc((size_t)512 * 1024 * 2);
    __hip_bfloat16* Wh1Th = (__hip_bfloat16*)alloc((size_t)512 * 512 * 2);
    float*          bqkv  = (float*)alloc(1600 * 4);
    float*          w1sum = (float*)alloc(1024 * 4);
    float*          b1f   = (float*)alloc(1024 * 4);
    float*          rk7   = (float*)alloc(7 * 512 * 4);
    float*          lanh  = (float*)alloc(Mc * 4);
    float*          lah   = (float*)alloc(Mc * 4);
    float*          zbuf  = (float*)alloc((size_t)Mc * 2 * 4);
    float*          stats = (float*)alloc((size_t)MP * 2 * 4);
    float* hout = (float*)d_out;

    hipMemsetAsync(d_out, 0, (size_t)out_size * sizeof(float), stream);
    init_kernel<<<(MP + 255) / 256, 256, 0, stream>>>(lanh, lah, zbuf, stats);
    pack_qkvT<<<(1536 * 512 + 255) / 256, 256, 0, stream>>>(Wq, Wk, Wv, WqkvT);
    transposeT<<<(512 * 512 + 255) / 256, 256, 0, stream>>>(Wo, WoT, 512, 512);
    transposeT_scale<<<(512 * 1024 + 255) / 256, 256, 0, stream>>>(W1, ln2s, W1T, 512, 1024);
    fold_w1<<<4, 256, 0, stream>>>(W1, ln2s, ln2o, b1, w1sum, b1f, 512, 1024);
    transposeT<<<(1024 * 512 + 255) / 256, 256, 0, stream>>>(W2, W2T, 1024, 512);
    transposeT<<<(512 * 512 + 255) / 256, 256, 0, stream>>>(Wh1, Wh1Th, 512, 512);
    pack_bias<<<(1536 + 255) / 256, 256, 0, stream>>>(bq, bk, bv, bqkv);
    rk7_kernel<<<7, 256, 0, stream>>>(pos, Wk, bk, rk7);
    fold_rl<<<(64 * 512 + 255) / 256, 256, 0, stream>>>(Wq, bq, rbias, rk7, WqkvT, bqkv);
    emb_kernel<<<Mc, 256, 0, stream>>>(x, We, eos, lnos, lnoo, h, hb);

    for (int it = 0; it < ITERS; ++it) {
        mgemm<3, 64><<<dim3(25, 33), 256, 0, stream>>>(
            hb, WqkvT, bqkv, nullptr, rlb, qkvb, nullptr, nullptr, Mc, 1600, 512);
        attn_mfma<<<dim3(5, 8, 16), 256, 0, stream>>>(qkvb, rlb, cbias, abufb);
        mgemm<5, 32><<<dim3(8, 66), 256, 0, stream>>>(
            abufb, WoT, bo, h, hmid, hmidb, stats, nullptr, Mc, 512, 512);
        mgemm<6, 64><<<dim3(16, 33), 256, 0, stream>>>(
            hmidb, W1T, b1f, nullptr, nullptr, g1b, stats, w1sum, Mc, 1024, 512);
        mgemm<4, 32><<<dim3(8, 66), 256, 0, stream>>>(
            g1b, W2T, b2, hmid, curr, chi, nullptr, nullptr, Mc, 512, 1024);
        halt_gemm<<<dim3(8, 66), 256, 0, stream>>>(chi, Wh1Th, bh1, Wh2, zbuf, Mc);
        haltblend<<<Mc / 4, 256, 0, stream>>>(curr, lnos, lnoo, zbuf, lanh, lah, h, hb, hout, stats);
    }
}

// Round 14
// 9639.933 us; speedup vs baseline: 1.1534x; 1.0012x over previous
//
#include <hip/hip_runtime.h>
#include <hip/hip_bf16.h>
#include <cstdint>
#include <cmath>

#define EPSLN 1e-5f

typedef __attribute__((ext_vector_type(8))) short bf16x8;
typedef __attribute__((ext_vector_type(4))) float f32x4;
typedef __attribute__((ext_vector_type(4))) unsigned short u16x4;

constexpr int Bc = 16;
constexpr int Sc = 129;          // T+1
constexpr int Mc = Bc * Sc;      // 2064 rows (real)
constexpr int MP = 2112;         // padded rows = 33*64 = 66*32
constexpr int ITERS = 127;       // T-1

__device__ __forceinline__ void gl2lds16(const void* g, void* l) {
    __builtin_amdgcn_global_load_lds(
        (const __attribute__((address_space(1))) unsigned int*)g,
        (__attribute__((address_space(3))) unsigned int*)l, 16, 0, 0);
}

template<int N> __device__ __forceinline__ void vmw() {
    if constexpr (N == 0) asm volatile("s_waitcnt vmcnt(0)" ::: "memory");
    else if constexpr (N == 3) asm volatile("s_waitcnt vmcnt(3)" ::: "memory");
    else if constexpr (N == 4) asm volatile("s_waitcnt vmcnt(4)" ::: "memory");
    else if constexpr (N == 6) asm volatile("s_waitcnt vmcnt(6)" ::: "memory");
}

__device__ __forceinline__ void bar() {
    __builtin_amdgcn_s_barrier();
    asm volatile("" ::: "memory");
}

__device__ __forceinline__ float bf2f(short s) {
    __hip_bfloat16 h;
    *reinterpret_cast<short*>(&h) = s;
    return __bfloat162float(h);
}
__device__ __forceinline__ short f2bf(float f) {
    __hip_bfloat16 h = __float2bfloat16(f);
    return *reinterpret_cast<short*>(&h);
}

// ---------------- bf16 MFMA GEMM: C = A @ Bt^T + epilogue ----------------
// A: [MP][K] bf16 row-major. Bt: [N][K] bf16 (weights pre-transposed).
// Double-buffered gl2lds staging with counted vmcnt (never 0 mid-loop).
// BM in {32,64}: 64 -> 2x2 waves of 32x32; 32 -> 1x4 waves of 32x16.
// EPI: 1 = bias -> Cf
//      3 = QKV+RL: col<1536 bias -> Cb (stride 1536); col>=1536 -> Cf f32 rl[row*64+col-1536]
//      4 = bias+res -> Cf(f32) + Cb(bf16)
//      5 = bias+res -> Cf(f32) AND Cb(bf16) + per-row (sum,sumsq) atomics -> stats
//      6 = epilogue-LN + gelu -> Cb:  v = rinv*acc - mean*rinv*aux[col] + bias[col]
template<int EPI, int BM>
__global__ __launch_bounds__(256)
void mgemm(const __hip_bfloat16* __restrict__ A, const __hip_bfloat16* __restrict__ Bt,
           const float* __restrict__ bias, const float* __restrict__ res,
           float* __restrict__ Cf, __hip_bfloat16* __restrict__ Cb,
           float* __restrict__ stats, const float* __restrict__ aux,
           int M, int N, int K)
{
    constexpr int ACH  = BM * 8;          // A tile 16B-chunks
    constexpr int ABYT = BM * 128;        // A tile bytes
    constexpr int STG  = ABYT + 8192;     // bytes per buffer (A + B)
    constexpr int LPT  = (ACH + 512) / 256; // gl2lds per thread per stage (4 or 3)
    constexpr int NI   = (BM == 64) ? 2 : 1;
    __shared__ char lds[2 * STG];
    const int tid = threadIdx.x;
    const int bm = blockIdx.y * BM, bn = blockIdx.x << 6;
    const int lane = tid & 63, wv = tid >> 6;
    const int wm = (BM == 64) ? ((wv & 1) << 5) : 0;
    const int wn = (BM == 64) ? ((wv >> 1) << 5) : (wv << 4);
    const int fr = lane & 15, kg = lane >> 4;

    int offA[2][2], offB[2][2];
    #pragma unroll
    for (int mi = 0; mi < 2; ++mi)
        #pragma unroll
        for (int kk = 0; kk < 2; ++kk) {
            int kb = (kk << 6) + (kg << 4);
            int ra = wm + (mi << 4) + fr;
            offA[mi][kk] = (ra << 7) + (kb ^ ((ra & 7) << 4));
        }
    #pragma unroll
    for (int ni = 0; ni < NI; ++ni)
        #pragma unroll
        for (int kk = 0; kk < 2; ++kk) {
            int kb = (kk << 6) + (kg << 4);
            int rb = wn + (ni << 4) + fr;
            offB[ni][kk] = ABYT + (rb << 7) + (kb ^ ((rb & 7) << 4));
        }

    auto stage = [&](int sb, int k0) {
        char* base = lds + sb * STG;
        #pragma unroll
        for (int c = 0; c < ACH / 256; ++c) {
            int idx = c * 256 + tid;
            int row = idx >> 3, kb = (idx & 7) << 4;
            gl2lds16((const char*)A + (((size_t)(bm + row) * K + k0) << 1) + (kb ^ ((row & 7) << 4)),
                     base + idx * 16);
        }
        #pragma unroll
        for (int c = 0; c < 2; ++c) {
            int idx = c * 256 + tid;
            int row = idx >> 3, kb = (idx & 7) << 4;
            gl2lds16((const char*)Bt + (((size_t)(bn + row) * K + k0) << 1) + (kb ^ ((row & 7) << 4)),
                     base + ABYT + idx * 16);
        }
    };

    f32x4 acc[2][2] = {};
    const int NK = K >> 6;
    stage(0, 0);
    for (int ks = 0; ks < NK; ++ks) {
        const int cur = ks & 1;
        if (ks + 1 < NK) { stage(cur ^ 1, (ks + 1) << 6); vmw<LPT>(); }
        else vmw<0>();
        bar();                               // stage ks data visible in LDS
        const char* bp = lds + cur * STG;
        bf16x8 af[2][2], bf_[2][2];
        #pragma unroll
        for (int mi = 0; mi < 2; ++mi)
            #pragma unroll
            for (int kk = 0; kk < 2; ++kk)
                af[mi][kk] = *(const bf16x8*)(bp + offA[mi][kk]);
        #pragma unroll
        for (int ni = 0; ni < NI; ++ni)
            #pragma unroll
            for (int kk = 0; kk < 2; ++kk)
                bf_[ni][kk] = *(const bf16x8*)(bp + offB[ni][kk]);
        #pragma unroll
        for (int kk = 0; kk < 2; ++kk)
            #pragma unroll
            for (int mi = 0; mi < 2; ++mi)
                #pragma unroll
                for (int ni = 0; ni < NI; ++ni)
                    acc[mi][ni] = __builtin_amdgcn_mfma_f32_16x16x32_bf16(
                        af[mi][kk], bf_[ni][kk], acc[mi][ni], 0, 0, 0);
        asm volatile("s_waitcnt lgkmcnt(0)" ::: "memory");
        bar();                               // buf[cur] reusable next+1 iter
    }

    const int rb4 = kg << 2;
    float b_[NI], w_[NI];
    #pragma unroll
    for (int ni = 0; ni < NI; ++ni) {
        int col = bn + wn + (ni << 4) + fr;
        b_[ni] = bias[col];
        if (EPI == 6) w_[ni] = aux[col];
    }
    #pragma unroll
    for (int mi = 0; mi < 2; ++mi)
        #pragma unroll
        for (int r = 0; r < 4; ++r) {
            const int row = bm + wm + (mi << 4) + rb4 + r;
            if (row >= M) continue;          // uniform over fr-group
            float mean = 0.f, rinv = 0.f;
            if (EPI == 6) {
                float s0 = stats[row * 2 + 0], s1 = stats[row * 2 + 1];
                mean = s0 * (1.f / 512.f);
                rinv = rsqrtf(s1 * (1.f / 512.f) - mean * mean + EPSLN);
            }
            float vs = 0.f, vq = 0.f;
            #pragma unroll
            for (int ni = 0; ni < NI; ++ni) {
                const int col = bn + wn + (ni << 4) + fr;
                float v = acc[mi][ni][r];
                if (EPI == 6) v = rinv * v - mean * rinv * w_[ni] + b_[ni];
                else v += b_[ni];
                if (EPI == 4 || EPI == 5) v += res[(size_t)row * N + col];
                if (EPI == 6) {
                    float g = 0.5f * v * (1.f + tanhf(0.7978845608028654f * (v + 0.044715f * v * v * v)));
                    Cb[(size_t)row * N + col] = __float2bfloat16(g);
                } else if (EPI == 3) {
                    if (col < 1536) Cb[(size_t)row * 1536 + col] = __float2bfloat16(v);
                    else            Cf[(size_t)row * 64 + (col - 1536)] = v;
                } else if (EPI == 4) {
                    Cf[(size_t)row * N + col] = v;
                    Cb[(size_t)row * N + col] = __float2bfloat16(v);
                } else if (EPI == 5) {
                    Cf[(size_t)row * N + col] = v;
                    Cb[(size_t)row * N + col] = __float2bfloat16(v);
                    vs += v; vq += v * v;
                } else {
                    Cf[(size_t)row * N + col] = v;
                }
            }
            if (EPI == 5) {
                #pragma unroll
                for (int m2 = 1; m2 < 16; m2 <<= 1) {
                    vs += __shfl_xor(vs, m2);
                    vq += __shfl_xor(vq, m2);
                }
                if (fr == 0) {
                    atomicAdd(&stats[row * 2 + 0], vs);
                    atomicAdd(&stats[row * 2 + 1], vq);
                }
            }
        }
}

// ---------------- halting GEMM: z[row][0:2] += tanh(chi@Wh1+bh1) @ Wh2 ----------------
// Plain bf16. N=K=512 fixed. BM=32, double-buffered.
__global__ __launch_bounds__(256)
void halt_gemm(const __hip_bfloat16* __restrict__ Ahp, const __hip_bfloat16* __restrict__ Bhp,
               const float* __restrict__ bh1, const float* __restrict__ Wh2,
               float* __restrict__ z, int M)
{
    constexpr int STG = 12288;   // Ah 4K @0, Bh 8K @4096
    __shared__ char lds[2 * STG];
    const int tid = threadIdx.x;
    const int bm = blockIdx.y << 5, bn = blockIdx.x << 6;
    const int lane = tid & 63, wv = tid >> 6;
    const int wn = wv << 4;
    const int fr = lane & 15, kg = lane >> 4;

    int offA[2][2], offB[2];
    #pragma unroll
    for (int mi = 0; mi < 2; ++mi)
        #pragma unroll
        for (int kk = 0; kk < 2; ++kk) {
            int kb = (kk << 6) + (kg << 4);
            int ra = (mi << 4) + fr;
            offA[mi][kk] = (ra << 7) + (kb ^ ((ra & 7) << 4));
        }
    #pragma unroll
    for (int kk = 0; kk < 2; ++kk) {
        int kb = (kk << 6) + (kg << 4);
        int rb = wn + fr;
        offB[kk] = 4096 + (rb << 7) + (kb ^ ((rb & 7) << 4));
    }

    auto stage = [&](int sb, int k0) {
        char* base = lds + sb * STG;
        {
            int row = tid >> 3, kb = (tid & 7) << 4;
            int swz = kb ^ ((row & 7) << 4);
            size_t aoff = (((size_t)(bm + row) * 512 + k0) << 1) + swz;
            gl2lds16((const char*)Ahp + aoff, base + tid * 16);
        }
        #pragma unroll
        for (int c = 0; c < 2; ++c) {
            int idx = c * 256 + tid;
            int row = idx >> 3, kb = (idx & 7) << 4;
            int swz = kb ^ ((row & 7) << 4);
            size_t boff = (((size_t)(bn + row) * 512 + k0) << 1) + swz;
            gl2lds16((const char*)Bhp + boff, base + 4096 + idx * 16);
        }
    };

    f32x4 acc[2] = {};
    stage(0, 0);
    for (int ks = 0; ks < 8; ++ks) {
        const int cur = ks & 1;
        if (ks < 7) { stage(cur ^ 1, (ks + 1) << 6); vmw<3>(); }
        else vmw<0>();
        bar();
        const char* bp = lds + cur * STG;
        bf16x8 ah[2][2], bh_[2];
        #pragma unroll
        for (int mi = 0; mi < 2; ++mi)
            #pragma unroll
            for (int kk = 0; kk < 2; ++kk)
                ah[mi][kk] = *(const bf16x8*)(bp + offA[mi][kk]);
        #pragma unroll
        for (int kk = 0; kk < 2; ++kk)
            bh_[kk] = *(const bf16x8*)(bp + offB[kk]);
        #pragma unroll
        for (int kk = 0; kk < 2; ++kk)
            #pragma unroll
            for (int mi = 0; mi < 2; ++mi)
                acc[mi] = __builtin_amdgcn_mfma_f32_16x16x32_bf16(ah[mi][kk], bh_[kk], acc[mi], 0, 0, 0);
        asm volatile("s_waitcnt lgkmcnt(0)" ::: "memory");
        bar();
    }

    const int col = bn + wn + fr;
    const float b_ = bh1[col];
    const float w0_ = Wh2[col * 2 + 0];
    const float w1_ = Wh2[col * 2 + 1];
    #pragma unroll
    for (int mi = 0; mi < 2; ++mi)
        #pragma unroll
        for (int r = 0; r < 4; ++r) {
            float v = tanhf(acc[mi][r] + b_);
            float p0 = v * w0_;
            float p1 = v * w1_;
            #pragma unroll
            for (int m2 = 1; m2 < 16; m2 <<= 1) {
                p0 += __shfl_xor(p0, m2);
                p1 += __shfl_xor(p1, m2);
            }
            if (fr == 0) {
                int row = bm + (mi << 4) + (kg << 2) + r;
                if (row < M) {
                    atomicAdd(&z[row * 2 + 0], p0);
                    atomicAdd(&z[row * 2 + 1], p1);
                }
            }
        }
}

// ---------------- MFMA attention ----------------
// grid (5 q-chunks, 8 heads, 16 batch), 256 threads. Q (with cbias pre-folded by
// the QKV GEMM bias), K, V from bf16 qkvb; rel logits precomputed into rl[MP][64].
// Two-barrier distributed in-register softmax; P aliases the dead KT region.
#define KT_BASE 0          // [144][128B] XOR-swizzled K (B-layout)   18432
#define P_BASE  0          // [32][336B] bf16 softmax — ALIASES KT    10752
#define VT_BASE 18432      // [64][384B] XOR-swizzled V^T             24576
#define QC_BASE 43008      // [32][72] bf16 q+cb (stride 144B)         4608
#define R_BASE  47616      // [32][8] f32 rel logits                   1024
#define WM_BASE 48640      // [4][32] f32 per-wave row max              512
#define WS_BASE 49152      // [4][32] f32 per-wave row sum              512
__global__ __launch_bounds__(256)
void attn_mfma(const __hip_bfloat16* __restrict__ qkvb,
               const float* __restrict__ rl,
               __hip_bfloat16* __restrict__ aout)
{
    __shared__ char lds[49664];
    const int tid = threadIdx.x;
    const int chunk = blockIdx.x, hh = blockIdx.y, b = blockIdx.z;
    const int q0 = chunk << 5;
    const int lane = tid & 63, wv = tid >> 6;
    const int fr = lane & 15, kg = lane >> 4;
    const size_t qrow0 = (size_t)b * Sc;
    const short* qs = (const short*)qkvb;

    // phase 0: zero VT bytes [256,384) per row (covers swizzled cols 128..191)
    // + Kt pad rows 129..143. XOR key<8 only permutes bits 4-6, closed in 128B window.
    {
        f32x4 zz = {};
        #pragma unroll
        for (int i = 0; i < 2; ++i) {
            int idx = i * 256 + tid;         // 512 chunks = 64 rows x 8 chunks of 16B
            int row = idx >> 3, ch = idx & 7;
            *(f32x4*)(lds + VT_BASE + row * 384 + 256 + ch * 16) = zz;
        }
        if (tid < 120)
            *(f32x4*)(lds + KT_BASE + 129 * 128 + tid * 16) = zz;
    }
    __syncthreads();

    // stage Kt (rows 0..128) via global_load_lds, XOR pre-swizzled source
    #pragma unroll
    for (int i = 0; i < 5; ++i) {
        int idx = i * 256 + tid;
        if (idx < 1152) {
            int row = idx >> 3, ch = idx & 7;
            if (row <= 128) {
                const char* src = (const char*)qkvb +
                    (((qrow0 + row) * 1536 + 512 + (size_t)hh * 64) << 1) + ((ch ^ (row & 7)) << 4);
                gl2lds16(src, lds + KT_BASE + idx * 16);
            }
        }
    }
    // stage V^T: swizzled scatter writes (conflict-free by key=(g^j))
    #pragma unroll
    for (int i = 0; i < 5; ++i) {
        int idx = i * 256 + tid;
        if (idx < 1032) {                    // 129 T-slots x 8 d-groups
            int T = idx >> 3, g = idx & 7;
            bf16x8 v = *(const bf16x8*)(qs + (qrow0 + T) * 1536 + 1024 + hh * 64 + g * 8);
            #pragma unroll
            for (int j = 0; j < 8; ++j) {
                int row = g * 8 + j;
                int key = (g ^ j) & 7;
                *(short*)(lds + VT_BASE + row * 384 + ((T * 2) ^ (key << 4))) = v[j];
            }
        }
    }
    // stage Qc (cbias already folded into QKV bias): straight bf16x8 copy
    {
        int row = tid >> 3, g = tid & 7;
        *(bf16x8*)(lds + QC_BASE + row * 144 + g * 16) =
            *(const bf16x8*)(qs + (qrow0 + q0 + row) * 1536 + hh * 64 + g * 8);
    }
    // R[row][c]: precomputed rel logits, coalesced f32 load
    if (tid < 224) {
        int row = tid / 7, c = tid % 7;
        *(float*)(lds + R_BASE + (row * 8 + c) * 4) =
            rl[(qrow0 + q0 + row) * 64 + hh * 8 + c];
    }
    __syncthreads();

    // QK^T: 9 N-tiles over 4 waves
    f32x4 acc[2][3] = {};
    __builtin_amdgcn_s_setprio(1);
    #pragma unroll
    for (int ni = 0; ni < 3; ++ni) {
        int nt = wv + ni * 4;
        if (nt > 8) continue;
        #pragma unroll
        for (int mt = 0; mt < 2; ++mt)
            #pragma unroll
            for (int ks = 0; ks < 2; ++ks) {
                bf16x8 a = *(const bf16x8*)(lds + QC_BASE + (mt * 16 + fr) * 144 + ks * 64 + kg * 16);
                int rowb = nt * 16 + fr;
                bf16x8 bb = *(const bf16x8*)(lds + KT_BASE + rowb * 128 +
                                             ((ks * 64 + kg * 16) ^ ((rowb & 7) << 4)));
                acc[mt][ni] = __builtin_amdgcn_mfma_f32_16x16x32_bf16(a, bb, acc[mt][ni], 0, 0, 0);
            }
    }
    __builtin_amdgcn_s_setprio(0);

    // s = (cl + rl)*scale, masked — in registers (overwrite acc)
    #pragma unroll
    for (int ni = 0; ni < 3; ++ni) {
        int nt = wv + ni * 4;
        int col = nt * 16 + fr;
        #pragma unroll
        for (int mt = 0; mt < 2; ++mt)
            #pragma unroll
            for (int r = 0; r < 4; ++r) {
                int row = mt * 16 + kg * 4 + r;
                float sv = -1e30f;
                if (nt <= 8 && col <= 128) {
                    int delta = q0 + row - col;
                    int c = delta >= 3 ? 3 : (delta <= -3 ? 4 : (delta < 0 ? delta + 7 : delta));
                    float rlv = *(const float*)(lds + R_BASE + (row * 8 + c) * 4);
                    sv = (acc[mt][ni][r] + rlv) * 0.125f;
                }
                acc[mt][ni][r] = sv;
            }
    }

    // distributed row max: in-lane (ni) + fr-group shfl + per-wave partials in LDS
    float m_[2][4];
    #pragma unroll
    for (int mt = 0; mt < 2; ++mt)
        #pragma unroll
        for (int r = 0; r < 4; ++r) {
            float m = fmaxf(fmaxf(acc[mt][0][r], acc[mt][1][r]), acc[mt][2][r]);
            #pragma unroll
            for (int b2 = 1; b2 < 16; b2 <<= 1) m = fmaxf(m, __shfl_xor(m, b2));
            m_[mt][r] = m;
        }
    if (fr == 0) {
        float* wm = (float*)(lds + WM_BASE) + (wv << 5);
        #pragma unroll
        for (int mt = 0; mt < 2; ++mt)
            #pragma unroll
            for (int r = 0; r < 4; ++r)
                wm[mt * 16 + (kg << 2) + r] = m_[mt][r];
    }
    __syncthreads();                        // bar1: all KT reads complete; P region free

    // zero P cols 144..159 (32 rows x 32B), safe after bar1
    if (tid < 128) {
        int row = tid >> 2;
        *(double*)(lds + P_BASE + row * 336 + 288 + (tid & 3) * 8) = 0.0;
    }

    // global max per row; exp; lane sums
    const float* wm = (const float*)(lds + WM_BASE);
    float gm[2][4], su[2][4];
    #pragma unroll
    for (int mt = 0; mt < 2; ++mt)
        #pragma unroll
        for (int r = 0; r < 4; ++r) {
            int row = mt * 16 + (kg << 2) + r;
            float g0 = fmaxf(wm[row], wm[32 + row]);
            float g1 = fmaxf(wm[64 + row], wm[96 + row]);
            gm[mt][r] = fmaxf(g0, g1);
            su[mt][r] = 0.f;
        }
    #pragma unroll
    for (int ni = 0; ni < 3; ++ni)
        #pragma unroll
        for (int mt = 0; mt < 2; ++mt)
            #pragma unroll
            for (int r = 0; r < 4; ++r) {
                float s = acc[mt][ni][r];
                float e = (s > -1e29f) ? expf(s - gm[mt][r]) : 0.f;
                acc[mt][ni][r] = e;
                su[mt][r] += e;
            }
    #pragma unroll
    for (int mt = 0; mt < 2; ++mt)
        #pragma unroll
        for (int r = 0; r < 4; ++r) {
            float s = su[mt][r];
            #pragma unroll
            for (int b2 = 1; b2 < 16; b2 <<= 1) s += __shfl_xor(s, b2);
            su[mt][r] = s;
        }
    if (fr == 0) {
        float* ws = (float*)(lds + WS_BASE) + (wv << 5);
        #pragma unroll
        for (int mt = 0; mt < 2; ++mt)
            #pragma unroll
            for (int r = 0; r < 4; ++r)
                ws[mt * 16 + (kg << 2) + r] = su[mt][r];
    }
    __syncthreads();                        // bar2

    const float* wsm = (const float*)(lds + WS_BASE);
    float inv_[2][4];
    #pragma unroll
    for (int mt = 0; mt < 2; ++mt)
        #pragma unroll
        for (int r = 0; r < 4; ++r) {
            int row = mt * 16 + (kg << 2) + r;
            float t = (wsm[row] + wsm[32 + row]) + (wsm[64 + row] + wsm[96 + row]);
            inv_[mt][r] = 1.f / t;
        }
    // P write (bf16) into aliased KT region
    #pragma unroll
    for (int ni = 0; ni < 3; ++ni) {
        int nt = wv + ni * 4;
        if (nt > 8) continue;
        int col = nt * 16 + fr;
        #pragma unroll
        for (int mt = 0; mt < 2; ++mt)
            #pragma unroll
            for (int r = 0; r < 4; ++r) {
                int row = mt * 16 + (kg << 2) + r;
                *(short*)(lds + P_BASE + row * 336 + col * 2) =
                    f2bf(acc[mt][ni][r] * inv_[mt][r]);
            }
    }
    __syncthreads();                        // bar3

    // PV: wave owns 16 output dims; V^T read with matching XOR swizzle
    f32x4 acc2[2] = {};
    const int rowv = wv * 16 + fr;
    const int keyv = ((rowv >> 3) ^ rowv) & 7;
    __builtin_amdgcn_s_setprio(1);
    #pragma unroll
    for (int mt = 0; mt < 2; ++mt)
        #pragma unroll
        for (int ks = 0; ks < 5; ++ks) {
            bf16x8 a  = *(const bf16x8*)(lds + P_BASE + (mt * 16 + fr) * 336 + ks * 64 + kg * 16);
            bf16x8 bb = *(const bf16x8*)(lds + VT_BASE + rowv * 384 +
                                         ((ks * 64 + kg * 16) ^ (keyv << 4)));
            acc2[mt] = __builtin_amdgcn_mfma_f32_16x16x32_bf16(a, bb, acc2[mt], 0, 0, 0);
        }
    __builtin_amdgcn_s_setprio(0);
    #pragma unroll
    for (int mt = 0; mt < 2; ++mt)
        #pragma unroll
        for (int r = 0; r < 4; ++r) {
            int t = q0 + mt * 16 + kg * 4 + r;
            if (t <= 128)
                aout[(qrow0 + t) * 512 + hh * 64 + wv * 16 + fr] = __float2bfloat16(acc2[mt][r]);
        }
}

// ---------------- ACT bookkeeping + LN(curr) + blend + h_out ----------------
// 4 rows per block, one 64-lane wave per row; no LDS, no syncthreads.
__global__ __launch_bounds__(256)
void haltblend(const float* __restrict__ curr, const float* __restrict__ s,
               const float* __restrict__ o, float* __restrict__ zbuf,
               float* __restrict__ lanh, float* __restrict__ lah,
               float* __restrict__ h, __hip_bfloat16* __restrict__ hb,
               float* __restrict__ hout, float* __restrict__ stats)
{
    const int row = (blockIdx.x << 2) + (threadIdx.x >> 6);
    const int lane = threadIdx.x & 63;

    float z0 = zbuf[row * 2 + 0] + 2.f;
    float z1 = zbuf[row * 2 + 1] - 2.f;
    float mxz = fmaxf(z0, z1);
    float lse = mxz + logf(expf(z0 - mxz) + expf(z1 - mxz));
    float lg0 = z0 - lse, lg1 = z1 - lse;
    float ln_ = lanh[row], la_ = lah[row];
    float lhalt = ln_ + lg1;
    float hl = expf(la_);            // PRE-update lah
    float ph = expf(lhalt);

    const size_t rbase = (size_t)row * 512;
    const int c0 = lane << 3;
    f32x4 x0 = *(const f32x4*)(curr + rbase + c0);
    f32x4 x1 = *(const f32x4*)(curr + rbase + c0 + 4);
    float sum = (x0[0] + x0[1]) + (x0[2] + x0[3]) + (x1[0] + x1[1]) + (x1[2] + x1[3]);
    float sq  = (x0[0] * x0[0] + x0[1] * x0[1]) + (x0[2] * x0[2] + x0[3] * x0[3])
              + (x1[0] * x1[0] + x1[1] * x1[1]) + (x1[2] * x1[2] + x1[3] * x1[3]);
    #pragma unroll
    for (int m2 = 1; m2 < 64; m2 <<= 1) { sum += __shfl_xor(sum, m2); sq += __shfl_xor(sq, m2); }
    float mean = sum * (1.f / 512.f);
    float inv = rsqrtf(sq * (1.f / 512.f) - mean * mean + EPSLN);

    if (lane == 0) {
        lanh[row] = ln_ + lg0;
        float m3 = fmaxf(la_, lhalt);
        lah[row] = m3 + logf(expf(la_ - m3) + expf(lhalt - m3));
        zbuf[row * 2 + 0] = 0.f;
        zbuf[row * 2 + 1] = 0.f;
        stats[row * 2 + 0] = 0.f;    // reset LN stats for next iteration's Wo epilogue
        stats[row * 2 + 1] = 0.f;
    }

    f32x4 sv0 = *(const f32x4*)(s + c0), sv1 = *(const f32x4*)(s + c0 + 4);
    f32x4 ov0 = *(const f32x4*)(o + c0), ov1 = *(const f32x4*)(o + c0 + 4);
    f32x4 hv0 = *(f32x4*)(h + rbase + c0), hv1 = *(f32x4*)(h + rbase + c0 + 4);
    f32x4 ho0 = *(f32x4*)(hout + rbase + c0), ho1 = *(f32x4*)(hout + rbase + c0 + 4);
    u16x4 hb0, hb1;
    #pragma unroll
    for (int e = 0; e < 4; ++e) {
        float cl = (x0[e] - mean) * inv * sv0[e] + ov0[e];
        float hn = hl * hv0[e] + (1.f - hl) * cl;
        hv0[e] = hn;
        __hip_bfloat16 bb = __float2bfloat16(hn);
        hb0[e] = *reinterpret_cast<unsigned short*>(&bb);
        ho0[e] += ph * cl;
    }
    #pragma unroll
    for (int e = 0; e < 4; ++e) {
        float cl = (x1[e] - mean) * inv * sv1[e] + ov1[e];
        float hn = hl * hv1[e] + (1.f - hl) * cl;
        hv1[e] = hn;
        __hip_bfloat16 bb = __float2bfloat16(hn);
        hb1[e] = *reinterpret_cast<unsigned short*>(&bb);
        ho1[e] += ph * cl;
    }
    *(f32x4*)(h + rbase + c0) = hv0;
    *(f32x4*)(h + rbase + c0 + 4) = hv1;
    *(u16x4*)(reinterpret_cast<unsigned short*>(hb) + rbase + c0) = hb0;
    *(u16x4*)(reinterpret_cast<unsigned short*>(hb) + rbase + c0 + 4) = hb1;
    *(f32x4*)(hout + rbase + c0) = ho0;
    *(f32x4*)(hout + rbase + c0 + 4) = ho1;
}

// ---------------- setup kernels ----------------
__global__ __launch_bounds__(256)
void emb_kernel(const float* __restrict__ x, const float* __restrict__ We,
                const float* __restrict__ eos, const float* __restrict__ s,
                const float* __restrict__ o, float* __restrict__ h,
                __hip_bfloat16* __restrict__ hb)
{
    int row = blockIdx.x, tid = threadIdx.x;
    int b = row / Sc, t = row % Sc;
    __shared__ float xs[64];
    if (t != 128 && tid < 64) xs[tid] = x[((size_t)b * 128 + t) * 64 + tid];
    __syncthreads();
    float v0, v1;
    if (t == 128) {
        v0 = eos[tid]; v1 = eos[tid + 256];
    } else {
        v0 = 0.f; v1 = 0.f;
        #pragma unroll 8
        for (int k = 0; k < 64; ++k) {
            float xv = xs[k];
            v0 = fmaf(xv, We[k * 512 + tid], v0);
            v1 = fmaf(xv, We[k * 512 + tid + 256], v1);
        }
    }
    float sum = v0 + v1, sq = v0 * v0 + v1 * v1;
    #pragma unroll
    for (int m2 = 1; m2 < 64; m2 <<= 1) { sum += __shfl_xor(sum, m2); sq += __shfl_xor(sq, m2); }
    __shared__ float ssum[4], ssq[4];
    if ((tid & 63) == 0) { ssum[tid >> 6] = sum; ssq[tid >> 6] = sq; }
    __syncthreads();
    float tot = ssum[0] + ssum[1] + ssum[2] + ssum[3];
    float totq = ssq[0] + ssq[1] + ssq[2] + ssq[3];
    float mean = tot * (1.f / 512.f);
    float inv = rsqrtf(totq * (1.f / 512.f) - mean * mean + EPSLN);
    float h0 = (v0 - mean) * inv * s[tid] + o[tid];
    float h1 = (v1 - mean) * inv * s[tid + 256] + o[tid + 256];
    h[(size_t)row * 512 + tid] = h0;
    h[(size_t)row * 512 + tid + 256] = h1;
    hb[(size_t)row * 512 + tid] = __float2bfloat16(h0);
    hb[(size_t)row * 512 + tid + 256] = __float2bfloat16(h1);
}

__global__ __launch_bounds__(256)
void rk7_kernel(const float* __restrict__ pos, const float* __restrict__ Wk,
                const float* __restrict__ bk, float* __restrict__ rk7)
{
    int c = blockIdx.x, tid = threadIdx.x;
    __shared__ float ps[512];
    ps[tid] = pos[c * 512 + tid];
    ps[tid + 256] = pos[c * 512 + tid + 256];
    __syncthreads();
    float a0 = bk[tid], a1 = bk[tid + 256];
    for (int k = 0; k < 512; ++k) {
        float pv = ps[k];
        a0 = fmaf(pv, Wk[(size_t)k * 512 + tid], a0);
        a1 = fmaf(pv, Wk[(size_t)k * 512 + tid + 256], a1);
    }
    rk7[c * 512 + tid] = a0;
    rk7[c * 512 + tid + 256] = a1;
}

__global__ __launch_bounds__(256)
void pack_qkvT(const float* __restrict__ Wq, const float* __restrict__ Wk,
               const float* __restrict__ Wv, __hip_bfloat16* __restrict__ Wt)
{
    int idx = blockIdx.x * 256 + threadIdx.x;
    if (idx >= 1536 * 512) return;
    int n = idx >> 9, k = idx & 511;
    const float* src = (n < 512) ? Wq : (n < 1024) ? Wk : Wv;
    int nc = n & 511;
    Wt[idx] = __float2bfloat16(src[(size_t)k * 512 + nc]);
}

// Append rl weights: Wt[1536 + h*8+c][k] = bf16( sum_d Wq[k][h*64+d]*rk7[c][h*64+d] )
// and bias bqkv[1536 + h*8+c] = sum_d (bq+rbias)[h*64+d]*rk7[c][h*64+d]. c==7 -> 0 pad.
__global__ __launch_bounds__(256)
void fold_rl(const float* __restrict__ Wq, const float* __restrict__ bq,
             const float* __restrict__ rbias, const float* __restrict__ rk7,
             __hip_bfloat16* __restrict__ Wt, float* __restrict__ bqkv)
{
    int idx = blockIdx.x * 256 + threadIdx.x;
    if (idx >= 64 * 512) return;
    int n = idx >> 9, k = idx & 511;
    int hh = n >> 3, c = n & 7;
    float a = 0.f;
    if (c < 7) {
        #pragma unroll 8
        for (int d = 0; d < 64; ++d)
            a = fmaf(Wq[(size_t)k * 512 + hh * 64 + d], rk7[c * 512 + hh * 64 + d], a);
    }
    Wt[(size_t)(1536 + n) * 512 + k] = __float2bfloat16(a);
    if (idx < 64) {
        int hh2 = idx >> 3, c2 = idx & 7;
        float s = 0.f;
        if (c2 < 7) {
            for (int d = 0; d < 64; ++d)
                s = fmaf(bq[hh2 * 64 + d] + rbias[hh2 * 64 + d], rk7[c2 * 512 + hh2 * 64 + d], s);
        }
        bqkv[1536 + idx] = s;
    }
}

__global__ __launch_bounds__(256)
void transposeT(const float* __restrict__ W, __hip_bfloat16* __restrict__ Wt, int K, int N)
{
    int idx = blockIdx.x * 256 + threadIdx.x;
    if (idx >= K * N) return;
    int n = idx / K, k = idx - n * K;
    Wt[idx] = __float2bfloat16(W[(size_t)k * N + n]);
}

// Wt[n][k] = bf16(W[k][n] * s[k])   (fold LN scale into W1)
__global__ __launch_bounds__(256)
void transposeT_scale(const float* __restrict__ W, const float* __restrict__ s,
                      __hip_bfloat16* __restrict__ Wt, int K, int N)
{
    int idx = blockIdx.x * 256 + threadIdx.x;
    if (idx >= K * N) return;
    int n = idx / K, k = idx - n * K;
    Wt[idx] = __float2bfloat16(W[(size_t)k * N + n] * s[k]);
}

// w1sum[n] = sum_k s[k]*W[k][n];  b1f[n] = b[n] + sum_k o[k]*W[k][n]
__global__ __launch_bounds__(256)
void fold_w1(const float* __restrict__ W, const float* __restrict__ s,
             const float* __restrict__ o, const float* __restrict__ b,
             float* __restrict__ w1sum, float* __restrict__ b1f, int K, int N)
{
    int n = blockIdx.x * 256 + threadIdx.x;
    if (n >= N) return;
    float ws = 0.f, bo_ = b[n];
    for (int k = 0; k < K; ++k) {
        float w = W[(size_t)k * N + n];
        ws = fmaf(s[k], w, ws);
        bo_ = fmaf(o[k], w, bo_);
    }
    w1sum[n] = ws;
    b1f[n] = bo_;
}

// bqkv[0..511] = bq + cbias (Q used only by attention Qc); 512..1023 bk; 1024..1535 bv
__global__ __launch_bounds__(256)
void pack_bias(const float* __restrict__ bq, const float* __restrict__ bk,
               const float* __restrict__ bv, const float* __restrict__ cbias,
               float* __restrict__ bqkv)
{
    int idx = blockIdx.x * 256 + threadIdx.x;
    if (idx < 1536)
        bqkv[idx] = (idx < 512) ? (bq[idx] + cbias[idx])
                  : (idx < 1024) ? bk[idx - 512] : bv[idx - 1024];
}

__global__ __launch_bounds__(256)
void init_kernel(float* __restrict__ lanh, float* __restrict__ lah,
                 float* __restrict__ zbuf, float* __restrict__ stats)
{
    int idx = blockIdx.x * 256 + threadIdx.x;
    if (idx < Mc) {
        lanh[idx] = 0.f; lah[idx] = -64.f;
        zbuf[idx * 2 + 0] = 0.f; zbuf[idx * 2 + 1] = 0.f;
    }
    if (idx < MP) {
        stats[idx * 2 + 0] = 0.f; stats[idx * 2 + 1] = 0.f;
    }
}

// ---------------- host launcher ----------------
extern "C" void kernel_launch(void* const* d_in, const int* in_sizes, int n_in,
                              void* d_out, int out_size, void* d_ws, size_t ws_size,
                              hipStream_t stream)
{
    const float* x     = (const float*)d_in[0];
    const float* We    = (const float*)d_in[1];
    const float* eos   = (const float*)d_in[2];
    const float* Wq    = (const float*)d_in[3];
    const float* bq    = (const float*)d_in[4];
    const float* Wk    = (const float*)d_in[5];
    const float* bk    = (const float*)d_in[6];
    const float* Wv    = (const float*)d_in[7];
    const float* bv    = (const float*)d_in[8];
    const float* Wo    = (const float*)d_in[9];
    const float* bo    = (const float*)d_in[10];
    const float* cbias = (const float*)d_in[11];
    const float* rbias = (const float*)d_in[12];
    const float* pos   = (const float*)d_in[13];
    const float* ln2s  = (const float*)d_in[14];
    const float* ln2o  = (const float*)d_in[15];
    const float* lnos  = (const float*)d_in[16];
    const float* lnoo  = (const float*)d_in[17];
    const float* W1    = (const float*)d_in[18];
    const float* b1    = (const float*)d_in[19];
    const float* W2    = (const float*)d_in[20];
    const float* b2    = (const float*)d_in[21];
    const float* Wh1   = (const float*)d_in[22];
    const float* bh1   = (const float*)d_in[23];
    const float* Wh2   = (const float*)d_in[24];
    (void)in_sizes; (void)n_in; (void)ws_size;

    char* wp = (char*)d_ws;
    auto alloc = [&](size_t bytes) { char* p = wp; wp += (bytes + 255) & ~(size_t)255; return p; };
    float*          h     = (float*)alloc((size_t)MP * 512 * 4);
    __hip_bfloat16* hb    = (__hip_bfloat16*)alloc((size_t)MP * 512 * 2);
    __hip_bfloat16* qkvb  = (__hip_bfloat16*)alloc((size_t)MP * 1536 * 2);
    float*          rlb   = (float*)alloc((size_t)MP * 64 * 4);
    __hip_bfloat16* abufb = (__hip_bfloat16*)alloc((size_t)MP * 512 * 2);
    float*          hmid  = (float*)alloc((size_t)MP * 512 * 4);
    __hip_bfloat16* hmidb = (__hip_bfloat16*)alloc((size_t)MP * 512 * 2);
    __hip_bfloat16* g1b   = (__hip_bfloat16*)alloc((size_t)MP * 1024 * 2);
    float*          curr  = (float*)alloc((size_t)MP * 512 * 4);
    __hip_bfloat16* chi   = (__hip_bfloat16*)alloc((size_t)MP * 512 * 2);
    __hip_bfloat16* WqkvT = (__hip_bfloat16*)alloc((size_t)1600 * 512 * 2);
    __hip_bfloat16* WoT   = (__hip_bfloat16*)alloc((size_t)512 * 512 * 2);
    __hip_bfloat16* W1T   = (__hip_bfloat16*)alloc((size_t)1024 * 512 * 2);
    __hip_bfloat16* W2T   = (__hip_bfloat16*)alloc((size_t)512 * 1024 * 2);
    __hip_bfloat16* Wh1Th = (__hip_bfloat16*)alloc((size_t)512 * 512 * 2);
    float*          bqkv  = (float*)alloc(1600 * 4);
    float*          w1sum = (float*)alloc(1024 * 4);
    float*          b1f   = (float*)alloc(1024 * 4);
    float*          rk7   = (float*)alloc(7 * 512 * 4);
    float*          lanh  = (float*)alloc(Mc * 4);
    float*          lah   = (float*)alloc(Mc * 4);
    float*          zbuf  = (float*)alloc((size_t)Mc * 2 * 4);
    float*          stats = (float*)alloc((size_t)MP * 2 * 4);
    float* hout = (float*)d_out;

    hipMemsetAsync(d_out, 0, (size_t)out_size * sizeof(float), stream);
    init_kernel<<<(MP + 255) / 256, 256, 0, stream>>>(lanh, lah, zbuf, stats);
    pack_qkvT<<<(1536 * 512 + 255) / 256, 256, 0, stream>>>(Wq, Wk, Wv, WqkvT);
    transposeT<<<(512 * 512 + 255) / 256, 256, 0, stream>>>(Wo, WoT, 512, 512);
    transposeT_scale<<<(512 * 1024 + 255) / 256, 256, 0, stream>>>(W1, ln2s, W1T, 512, 1024);
    fold_w1<<<4, 256, 0, stream>>>(W1, ln2s, ln2o, b1, w1sum, b1f, 512, 1024);
    transposeT<<<(1024 * 512 + 255) / 256, 256, 0, stream>>>(W2, W2T, 1024, 512);
    transposeT<<<(512 * 512 + 255) / 256, 256, 0, stream>>>(Wh1, Wh1Th, 512, 512);
    pack_bias<<<(1536 + 255) / 256, 256, 0, stream>>>(bq, bk, bv, cbias, bqkv);
    rk7_kernel<<<7, 256, 0, stream>>>(pos, Wk, bk, rk7);
    fold_rl<<<(64 * 512 + 255) / 256, 256, 0, stream>>>(Wq, bq, rbias, rk7, WqkvT, bqkv);
    emb_kernel<<<Mc, 256, 0, stream>>>(x, We, eos, lnos, lnoo, h, hb);

    for (int it = 0; it < ITERS; ++it) {
        mgemm<3, 64><<<dim3(25, 33), 256, 0, stream>>>(
            hb, WqkvT, bqkv, nullptr, rlb, qkvb, nullptr, nullptr, Mc, 1600, 512);
        attn_mfma<<<dim3(5, 8, 16), 256, 0, stream>>>(qkvb, rlb, abufb);
        mgemm<5, 32><<<dim3(8, 66), 256, 0, stream>>>(
            abufb, WoT, bo, h, hmid, hmidb, stats, nullptr, Mc, 512, 512);
        mgemm<6, 64><<<dim3(16, 33), 256, 0, stream>>>(
            hmidb, W1T, b1f, nullptr, nullptr, g1b, stats, w1sum, Mc, 1024, 512);
        mgemm<4, 32><<<dim3(8, 66), 256, 0, stream>>>(
            g1b, W2T, b2, hmid, curr, chi, nullptr, nullptr, Mc, 512, 1024);
        halt_gemm<<<dim3(8, 66), 256, 0, stream>>>(chi, Wh1Th, bh1, Wh2, zbuf, Mc);
        haltblend<<<Mc / 4, 256, 0, stream>>>(curr, lnos, lnoo, zbuf, lanh, lah, h, hb, hout, stats);
    }
}